// Round 1
// baseline (1010.315 us; speedup 1.0000x reference)
//
#include <hip/hip_runtime.h>
#include <hip/hip_bf16.h>
#include <float.h>

#define NTOK 8192   // B*G tokens
#define NCB  8192   // codebook entries
#define CDIM 256
#define KPTS 32

// ---------------- cnorm: |c_n|^2 ----------------
__global__ __launch_bounds__(256) void cnorm_k(const float* __restrict__ cb,
                                               float* __restrict__ cnorm) {
  int wave = threadIdx.x >> 6, lane = threadIdx.x & 63;
  int row = blockIdx.x * 4 + wave;
  const float4* r = (const float4*)(cb + (size_t)row * CDIM);
  float4 v = r[lane];                       // 64 lanes x 4 floats = 256
  float s = v.x * v.x + v.y * v.y + v.z * v.z + v.w * v.w;
#pragma unroll
  for (int off = 32; off; off >>= 1) s += __shfl_down(s, off, 64);
  if (lane == 0) cnorm[row] = s;
}

// ---------------- transpose [O][Cin] -> [Cin][O] ----------------
__global__ __launch_bounds__(256) void transpose_k(const float* __restrict__ in,
                                                   float* __restrict__ out,
                                                   int O, int Cin) {
  int idx = blockIdx.x * 256 + threadIdx.x;
  if (idx < O * Cin) {
    int c = idx / O;
    int o = idx - c * O;
    out[idx] = in[o * Cin + c];
  }
}

// ---------------- fused distance GEMM + argmin ----------------
#define BM 64
#define BN 128
#define BKT 32
#define NSPLIT 4
#define NPART (NCB / NSPLIT)   // 2048

__global__ __launch_bounds__(256) void argmin_k(const float* __restrict__ pf,
                                                const float* __restrict__ cb,
                                                const float* __restrict__ cnorm,
                                                float* __restrict__ pv,
                                                int* __restrict__ pi) {
  __shared__ float As[BM][BKT + 4];
  __shared__ float Bs[BN][BKT + 4];
  __shared__ float redv[BM][16];
  __shared__ int   redi[BM][16];
  int tid = threadIdx.x, tx = tid & 15, ty = tid >> 4;
  int tb = blockIdx.x & 127;   // token tile (128 tiles of 64)
  int sp = blockIdx.x >> 7;    // codebook split 0..3
  int row0 = tb * BM, nbase = sp * NPART;

  float bestv[4];
  int besti[4];
#pragma unroll
  for (int i = 0; i < 4; i++) { bestv[i] = FLT_MAX; besti[i] = 0x7fffffff; }

  for (int nt = 0; nt < NPART / BN; ++nt) {
    int n0 = nbase + nt * BN;
    float acc[4][8];
#pragma unroll
    for (int i = 0; i < 4; i++)
#pragma unroll
      for (int j = 0; j < 8; j++) acc[i][j] = 0.f;

    for (int kt = 0; kt < CDIM / BKT; ++kt) {
      int k0 = kt * BKT;
#pragma unroll
      for (int s = 0; s < 2; s++) {
        int v = tid + s * 256, r = v >> 3, c4 = v & 7;
        *(float4*)&As[r][c4 * 4] =
            *(const float4*)(pf + (size_t)(row0 + r) * CDIM + k0 + c4 * 4);
      }
#pragma unroll
      for (int s = 0; s < 4; s++) {
        int v = tid + s * 256, r = v >> 3, c4 = v & 7;
        *(float4*)&Bs[r][c4 * 4] =
            *(const float4*)(cb + (size_t)(n0 + r) * CDIM + k0 + c4 * 4);
      }
      __syncthreads();
#pragma unroll
      for (int kk = 0; kk < BKT; kk += 4) {
        float4 a[4], b[8];
#pragma unroll
        for (int i = 0; i < 4; i++) a[i] = *(float4*)&As[ty + 16 * i][kk];
#pragma unroll
        for (int j = 0; j < 8; j++) b[j] = *(float4*)&Bs[tx + 16 * j][kk];
#pragma unroll
        for (int i = 0; i < 4; i++)
#pragma unroll
          for (int j = 0; j < 8; j++)
            acc[i][j] += a[i].x * b[j].x + a[i].y * b[j].y +
                         a[i].z * b[j].z + a[i].w * b[j].w;
      }
      __syncthreads();
    }
    // fold tile into running argmin (d = |c|^2 - 2 p.c ; |p|^2 dropped)
#pragma unroll
    for (int j = 0; j < 8; j++) {
      int col = n0 + tx + 16 * j;
      float cn = cnorm[col];
#pragma unroll
      for (int i = 0; i < 4; i++) {
        float d = cn - 2.f * acc[i][j];
        if (d < bestv[i] || (d == bestv[i] && col < besti[i])) {
          bestv[i] = d; besti[i] = col;
        }
      }
    }
  }
#pragma unroll
  for (int i = 0; i < 4; i++) {
    redv[ty + 16 * i][tx] = bestv[i];
    redi[ty + 16 * i][tx] = besti[i];
  }
  __syncthreads();
  if (tid < BM) {
    float bv = redv[tid][0]; int bi = redi[tid][0];
#pragma unroll
    for (int t = 1; t < 16; t++) {
      float v = redv[tid][t]; int ii = redi[tid][t];
      if (v < bv || (v == bv && ii < bi)) { bv = v; bi = ii; }
    }
    pv[sp * NTOK + row0 + tid] = bv;
    pi[sp * NTOK + row0 + tid] = bi;
  }
}

// ---------------- merge N-splits ----------------
__global__ __launch_bounds__(256) void merge_k(const float* __restrict__ pv,
                                               const int* __restrict__ pi,
                                               int* __restrict__ ids) {
  int t = blockIdx.x * 256 + threadIdx.x;
  if (t < NTOK) {
    float bv = pv[t]; int bi = pi[t];
#pragma unroll
    for (int s = 1; s < NSPLIT; s++) {
      float v = pv[s * NTOK + t]; int ii = pi[s * NTOK + t];
      if (v < bv || (v == bv && ii < bi)) { bv = v; bi = ii; }
    }
    ids[t] = bi;
  }
}

// ---------------- fused gather + MLP + chamfer ----------------
__global__ __launch_bounds__(256) void mlp_chamfer_k(
    const float* __restrict__ cb, const int* __restrict__ ids,
    const float* __restrict__ w1T, const float* __restrict__ b1,
    const float* __restrict__ w2T, const float* __restrict__ b2,
    const float* __restrict__ w3T, const float* __restrict__ b3,
    const float* __restrict__ neigh, float* __restrict__ out) {
  __shared__ float qs[16][256];
  __shared__ float hs[16][512];
  __shared__ float h2s[16][256];
  __shared__ float rec[16][96];
  __shared__ float gts[16][96];
  __shared__ int sid[16];
  __shared__ float wsum[4];
  int tid = threadIdx.x;
  int t0 = blockIdx.x * 16;

  if (tid < 16) sid[tid] = ids[t0 + tid];
  __syncthreads();
  // gather quantized vectors
#pragma unroll
  for (int s = 0; s < 4; s++) {
    int v = tid + s * 256, t = v >> 6, c4 = v & 63;
    *(float4*)&qs[t][c4 * 4] = *(const float4*)(cb + (size_t)sid[t] * CDIM + c4 * 4);
  }
  __syncthreads();

  // ----- layer 1: 256 -> 512, relu. thread owns outputs 2*tid, 2*tid+1 -----
  {
    float2 acc[16];
#pragma unroll
    for (int t = 0; t < 16; t++) acc[t] = make_float2(0.f, 0.f);
    const float2* w = (const float2*)w1T;   // [256][256 float2]
    for (int k0 = 0; k0 < 256; k0 += 4) {
      float2 w0 = w[(k0 + 0) * 256 + tid];
      float2 w1v = w[(k0 + 1) * 256 + tid];
      float2 w2v = w[(k0 + 2) * 256 + tid];
      float2 w3v = w[(k0 + 3) * 256 + tid];
#pragma unroll
      for (int t = 0; t < 16; t++) {
        float4 q = *(float4*)&qs[t][k0];
        acc[t].x += w0.x * q.x + w1v.x * q.y + w2v.x * q.z + w3v.x * q.w;
        acc[t].y += w0.y * q.x + w1v.y * q.y + w2v.y * q.z + w3v.y * q.w;
      }
    }
    float2 bb = ((const float2*)b1)[tid];
#pragma unroll
    for (int t = 0; t < 16; t++) {
      float2 h;
      h.x = fmaxf(acc[t].x + bb.x, 0.f);
      h.y = fmaxf(acc[t].y + bb.y, 0.f);
      *(float2*)&hs[t][2 * tid] = h;
    }
  }
  __syncthreads();

  // ----- layer 2: 512 -> 256, relu. thread owns output tid -----
  {
    float acc[16];
#pragma unroll
    for (int t = 0; t < 16; t++) acc[t] = 0.f;
    for (int k0 = 0; k0 < 512; k0 += 4) {
      float w0 = w2T[(k0 + 0) * 256 + tid];
      float w1v = w2T[(k0 + 1) * 256 + tid];
      float w2v = w2T[(k0 + 2) * 256 + tid];
      float w3v = w2T[(k0 + 3) * 256 + tid];
#pragma unroll
      for (int t = 0; t < 16; t++) {
        float4 h = *(float4*)&hs[t][k0];
        acc[t] += w0 * h.x + w1v * h.y + w2v * h.z + w3v * h.w;
      }
    }
    float bb = b2[tid];
#pragma unroll
    for (int t = 0; t < 16; t++) h2s[t][tid] = fmaxf(acc[t] + bb, 0.f);
  }
  __syncthreads();

  // ----- layer 3: 256 -> 96, no relu. threads 0..191: (half of tokens) x o -----
  if (tid < 192) {
    int grp = tid / 96;            // 0 or 1
    int o = tid - grp * 96;
    int tb = grp * 8;
    float acc[8];
#pragma unroll
    for (int t = 0; t < 8; t++) acc[t] = 0.f;
    for (int k0 = 0; k0 < 256; k0 += 4) {
      float w0 = w3T[(k0 + 0) * 96 + o];
      float w1v = w3T[(k0 + 1) * 96 + o];
      float w2v = w3T[(k0 + 2) * 96 + o];
      float w3v = w3T[(k0 + 3) * 96 + o];
#pragma unroll
      for (int t = 0; t < 8; t++) {
        float4 h = *(float4*)&h2s[tb + t][k0];
        acc[t] += w0 * h.x + w1v * h.y + w2v * h.z + w3v * h.w;
      }
    }
    float bb = b3[o];
#pragma unroll
    for (int t = 0; t < 8; t++) rec[tb + t][o] = acc[t] + bb;
  }
  // stage ground truth points
#pragma unroll
  for (int s = 0; s < 6; s++) {
    int v = tid + s * 256;
    int t = v / 96, c = v - 96 * t;
    gts[t][c] = neigh[(size_t)(t0 + t) * 96 + c];
  }
  __syncthreads();

  // ----- chamfer: both directions -----
  float local = 0.f;
#pragma unroll
  for (int pp = 0; pp < 2; ++pp) {
    int p = tid + pp * 256;
    int t = p >> 5, i = p & 31;
    float rx = rec[t][3 * i], ry = rec[t][3 * i + 1], rz = rec[t][3 * i + 2];
    float gx = gts[t][3 * i], gy = gts[t][3 * i + 1], gz = gts[t][3 * i + 2];
    float mA = FLT_MAX, mB = FLT_MAX;
#pragma unroll
    for (int j = 0; j < 32; j++) {
      float dx = rx - gts[t][3 * j], dy = ry - gts[t][3 * j + 1], dz = rz - gts[t][3 * j + 2];
      float d = dx * dx + dy * dy + dz * dz;
      mA = fminf(mA, d);
      dx = rec[t][3 * j] - gx; dy = rec[t][3 * j + 1] - gy; dz = rec[t][3 * j + 2] - gz;
      d = dx * dx + dy * dy + dz * dz;
      mB = fminf(mB, d);
    }
    local += mA + mB;
  }
#pragma unroll
  for (int off = 32; off; off >>= 1) local += __shfl_down(local, off, 64);
  if ((tid & 63) == 0) wsum[tid >> 6] = local;
  __syncthreads();
  if (tid == 0) {
    float s = wsum[0] + wsum[1] + wsum[2] + wsum[3];
    atomicAdd(out, s * (1.0f / (float)(NTOK * KPTS)));
  }
}

extern "C" void kernel_launch(void* const* d_in, const int* in_sizes, int n_in,
                              void* d_out, int out_size, void* d_ws, size_t ws_size,
                              hipStream_t stream) {
  const float* pf    = (const float*)d_in[0];
  const float* neigh = (const float*)d_in[1];
  const float* cb    = (const float*)d_in[2];
  const float* w1    = (const float*)d_in[3];
  const float* b1    = (const float*)d_in[4];
  const float* w2    = (const float*)d_in[5];
  const float* b2    = (const float*)d_in[6];
  const float* w3    = (const float*)d_in[7];
  const float* b3    = (const float*)d_in[8];
  float* out = (float*)d_out;
  float* ws = (float*)d_ws;

  float* cnorm = ws;                   // 8192
  float* pv    = ws + 8192;            // 4*8192
  float* w1T   = ws + 40960;           // 131072
  float* w2T   = ws + 172032;          // 131072
  float* w3T   = ws + 303104;          // 24576
  int*   pi    = (int*)(ws + 327680);  // 4*8192
  int*   ids   = (int*)(ws + 360448);  // 8192

  hipMemsetAsync(d_out, 0, sizeof(float), stream);
  cnorm_k<<<NCB / 4, 256, 0, stream>>>(cb, cnorm);
  transpose_k<<<512, 256, 0, stream>>>(w1, w1T, 512, 256);
  transpose_k<<<512, 256, 0, stream>>>(w2, w2T, 256, 512);
  transpose_k<<<96, 256, 0, stream>>>(w3, w3T, 96, 256);
  argmin_k<<<128 * NSPLIT, 256, 0, stream>>>(pf, cb, cnorm, pv, pi);
  merge_k<<<NTOK / 256, 256, 0, stream>>>(pv, pi, ids);
  mlp_chamfer_k<<<NTOK / 16, 256, 0, stream>>>(cb, ids, w1T, b1, w2T, b2, w3T, b3, neigh, out);
}

// Round 2
// 338.058 us; speedup vs baseline: 2.9886x; 2.9886x over previous
//
#include <hip/hip_runtime.h>
#include <hip/hip_bf16.h>
#include <float.h>

#define NTOK 8192   // B*G tokens
#define NCB  8192   // codebook entries
#define CDIM 256
#define KPTS 32
#define GAP  40     // padded row length (ushorts) per 32-k block: 32 data + 8 pad

typedef unsigned short ushort_t;
typedef __attribute__((ext_vector_type(8))) short short8;   // 8 bf16 (4 VGPRs)
typedef __attribute__((ext_vector_type(4))) float f32x4;
typedef unsigned int u32;

__device__ __forceinline__ void gl_lds16(const ushort* g, ushort* l) {
  __builtin_amdgcn_global_load_lds(
      (const __attribute__((address_space(1))) u32*)(g),
      (__attribute__((address_space(3))) u32*)(l), 16, 0, 0);
}

// ---------------- cnorm: |c_n|^2 (fp32 exact) ----------------
__global__ __launch_bounds__(256) void cnorm_k(const float* __restrict__ cb,
                                               float* __restrict__ cnorm) {
  int wave = threadIdx.x >> 6, lane = threadIdx.x & 63;
  int row = blockIdx.x * 4 + wave;
  const float4* r = (const float4*)(cb + (size_t)row * CDIM);
  float4 v = r[lane];
  float s = v.x * v.x + v.y * v.y + v.z * v.z + v.w * v.w;
#pragma unroll
  for (int off = 32; off; off >>= 1) s += __shfl_down(s, off, 64);
  if (lane == 0) cnorm[row] = s;
}

// ------- fp32 -> bf16 hi/lo, K-blocked padded layout [8][8192][GAP] -------
__global__ __launch_bounds__(256) void cvt_k(const float* __restrict__ in,
                                             ushort* __restrict__ hi,
                                             ushort* __restrict__ lo) {
  int idx = blockIdx.x * 256 + threadIdx.x;   // one per float4; 8192*64 total
  int row = idx >> 6, k4 = idx & 63;
  float4 v = ((const float4*)in)[idx];
  int kb = k4 >> 3, kkq = (k4 & 7) * 4;
  size_t o = ((size_t)kb * 8192 + row) * GAP + kkq;
  float x[4] = {v.x, v.y, v.z, v.w};
  ushort h[4], l[4];
#pragma unroll
  for (int e = 0; e < 4; e++) {
    u32 u = __float_as_uint(x[e]);
    u32 hb = (u + 0x7fffu + ((u >> 16) & 1u)) & 0xffff0000u;  // RNE to bf16
    float hf = __uint_as_float(hb);
    float lf = x[e] - hf;
    u32 ul = __float_as_uint(lf);
    u32 lb = ul + 0x7fffu + ((ul >> 16) & 1u);
    h[e] = (ushort)(hb >> 16);
    l[e] = (ushort)(lb >> 16);
  }
  *(ushort4*)(hi + o) = make_ushort4(h[0], h[1], h[2], h[3]);
  *(ushort4*)(lo + o) = make_ushort4(l[0], l[1], l[2], l[3]);
}

// ---------------- transpose [O][Cin] -> [Cin][O] ----------------
__global__ __launch_bounds__(256) void transpose_k(const float* __restrict__ in,
                                                   float* __restrict__ out,
                                                   int O, int Cin) {
  int idx = blockIdx.x * 256 + threadIdx.x;
  if (idx < O * Cin) {
    int c = idx / O;
    int o = idx - c * O;
    out[idx] = in[o * Cin + c];
  }
}

// -------- fused MFMA distance GEMM + per-tile argmin --------
// d = |c|^2 - 2 p.c  (|p|^2 row-constant, dropped)
// p.c via split bf16: ah*bh + ah*bl + al*bh  (~fp32 accuracy)
__global__ __launch_bounds__(256, 2) void argmin_k(
    const ushort* __restrict__ Ahg, const ushort* __restrict__ Alg,
    const ushort* __restrict__ Bhg, const ushort* __restrict__ Blg,
    const float* __restrict__ cnorm,
    float* __restrict__ pv, int* __restrict__ pi) {
  __shared__ ushort lds[4 * 128 * GAP];
  int tid = threadIdx.x;
  int nt = blockIdx.x, mt = blockIdx.y;   // x = n fast for L2 reuse of A
  int wv = tid >> 6, lane = tid & 63;
  int quad = lane >> 4, r16 = lane & 15;
  int wr = wv >> 1, wc = wv & 1;

  ushort* Ah = lds;
  ushort* Al = lds + 128 * GAP;
  ushort* Bh = lds + 2 * 128 * GAP;
  ushort* Bl = lds + 3 * 128 * GAP;

  f32x4 acc[4][4];
#pragma unroll
  for (int i = 0; i < 4; i++)
#pragma unroll
    for (int j = 0; j < 4; j++) acc[i][j] = (f32x4){0.f, 0.f, 0.f, 0.f};

  // each wave stages one of the 4 arrays (contiguous 10 KiB per k-block)
  const ushort* sarr = (wv == 0) ? Ahg : (wv == 1) ? Alg : (wv == 2) ? Bhg : Blg;
  int r0 = (wv < 2 ? mt : nt) * 128;
  ushort* ldst = lds + wv * 128 * GAP;

  for (int kb = 0; kb < 8; ++kb) {
    const ushort* gp = sarr + ((size_t)kb * 8192 + r0) * GAP + lane * 8;
#pragma unroll
    for (int c = 0; c < 10; ++c) gl_lds16(gp + c * 512, ldst + c * 512);
    __syncthreads();

    int koff = quad * 8;
    short8 fah[4], fal[4], fbh[4], fbl[4];
#pragma unroll
    for (int i = 0; i < 4; i++) {
      int row = wr * 64 + i * 16 + r16;
      fah[i] = *(const short8*)(Ah + row * GAP + koff);
      fal[i] = *(const short8*)(Al + row * GAP + koff);
    }
#pragma unroll
    for (int j = 0; j < 4; j++) {
      int col = wc * 64 + j * 16 + r16;
      fbh[j] = *(const short8*)(Bh + col * GAP + koff);
      fbl[j] = *(const short8*)(Bl + col * GAP + koff);
    }
#pragma unroll
    for (int i = 0; i < 4; i++)
#pragma unroll
      for (int j = 0; j < 4; j++) {
        acc[i][j] = __builtin_amdgcn_mfma_f32_16x16x32_bf16(fah[i], fbh[j], acc[i][j], 0, 0, 0);
        acc[i][j] = __builtin_amdgcn_mfma_f32_16x16x32_bf16(fah[i], fbl[j], acc[i][j], 0, 0, 0);
        acc[i][j] = __builtin_amdgcn_mfma_f32_16x16x32_bf16(fal[i], fbh[j], acc[i][j], 0, 0, 0);
      }
    __syncthreads();
  }

  // epilogue: per-row argmin over this block's 128 cols
  // C/D layout: col = lane&15 (r16), row = quad*4 + reg
#pragma unroll
  for (int i = 0; i < 4; i++) {
    float bv[4];
    int bi[4];
#pragma unroll
    for (int reg = 0; reg < 4; reg++) { bv[reg] = FLT_MAX; bi[reg] = 0x7fffffff; }
#pragma unroll
    for (int j = 0; j < 4; j++) {
      int col = nt * 128 + wc * 64 + j * 16 + r16;
      float cn = cnorm[col];
#pragma unroll
      for (int reg = 0; reg < 4; reg++) {
        float d = cn - 2.f * acc[i][j][reg];
        if (d < bv[reg] || (d == bv[reg] && col < bi[reg])) { bv[reg] = d; bi[reg] = col; }
      }
    }
#pragma unroll
    for (int m = 1; m < 16; m <<= 1) {
#pragma unroll
      for (int reg = 0; reg < 4; reg++) {
        float ov = __shfl_xor(bv[reg], m, 64);
        int oi = __shfl_xor(bi[reg], m, 64);
        if (ov < bv[reg] || (ov == bv[reg] && oi < bi[reg])) { bv[reg] = ov; bi[reg] = oi; }
      }
    }
    if (r16 == 0) {
#pragma unroll
      for (int reg = 0; reg < 4; reg++) {
        int row = mt * 128 + wr * 64 + i * 16 + quad * 4 + reg;
        pv[(size_t)nt * NTOK + row] = bv[reg];
        pi[(size_t)nt * NTOK + row] = bi[reg];
      }
    }
  }
}

// ---------------- merge 64 N-tiles ----------------
__global__ __launch_bounds__(256) void merge_k(const float* __restrict__ pv,
                                               const int* __restrict__ pi,
                                               int* __restrict__ ids) {
  int t = blockIdx.x * 256 + threadIdx.x;
  float bv = FLT_MAX;
  int bi = 0x7fffffff;
#pragma unroll 8
  for (int s = 0; s < 64; s++) {
    float v = pv[(size_t)s * NTOK + t];
    int ii = pi[(size_t)s * NTOK + t];
    if (v < bv || (v == bv && ii < bi)) { bv = v; bi = ii; }
  }
  ids[t] = bi;
}

// ---------------- fused gather + MLP + chamfer ----------------
__global__ __launch_bounds__(256) void mlp_chamfer_k(
    const float* __restrict__ cb, const int* __restrict__ ids,
    const float* __restrict__ w1T, const float* __restrict__ b1,
    const float* __restrict__ w2T, const float* __restrict__ b2,
    const float* __restrict__ w3T, const float* __restrict__ b3,
    const float* __restrict__ neigh, float* __restrict__ out) {
  __shared__ float qs[16][256];
  __shared__ float hs[16][512];
  __shared__ float h2s[16][256];
  __shared__ float rec[16][96];
  __shared__ float gts[16][96];
  __shared__ int sid[16];
  __shared__ float wsum[4];
  int tid = threadIdx.x;
  int t0 = blockIdx.x * 16;

  if (tid < 16) sid[tid] = ids[t0 + tid];
  __syncthreads();
#pragma unroll
  for (int s = 0; s < 4; s++) {
    int v = tid + s * 256, t = v >> 6, c4 = v & 63;
    *(float4*)&qs[t][c4 * 4] = *(const float4*)(cb + (size_t)sid[t] * CDIM + c4 * 4);
  }
  __syncthreads();

  {
    float2 acc[16];
#pragma unroll
    for (int t = 0; t < 16; t++) acc[t] = make_float2(0.f, 0.f);
    const float2* w = (const float2*)w1T;
    for (int k0 = 0; k0 < 256; k0 += 4) {
      float2 w0 = w[(k0 + 0) * 256 + tid];
      float2 w1v = w[(k0 + 1) * 256 + tid];
      float2 w2v = w[(k0 + 2) * 256 + tid];
      float2 w3v = w[(k0 + 3) * 256 + tid];
#pragma unroll
      for (int t = 0; t < 16; t++) {
        float4 q = *(float4*)&qs[t][k0];
        acc[t].x += w0.x * q.x + w1v.x * q.y + w2v.x * q.z + w3v.x * q.w;
        acc[t].y += w0.y * q.x + w1v.y * q.y + w2v.y * q.z + w3v.y * q.w;
      }
    }
    float2 bb = ((const float2*)b1)[tid];
#pragma unroll
    for (int t = 0; t < 16; t++) {
      float2 h;
      h.x = fmaxf(acc[t].x + bb.x, 0.f);
      h.y = fmaxf(acc[t].y + bb.y, 0.f);
      *(float2*)&hs[t][2 * tid] = h;
    }
  }
  __syncthreads();

  {
    float acc[16];
#pragma unroll
    for (int t = 0; t < 16; t++) acc[t] = 0.f;
    for (int k0 = 0; k0 < 512; k0 += 4) {
      float w0 = w2T[(k0 + 0) * 256 + tid];
      float w1v = w2T[(k0 + 1) * 256 + tid];
      float w2v = w2T[(k0 + 2) * 256 + tid];
      float w3v = w2T[(k0 + 3) * 256 + tid];
#pragma unroll
      for (int t = 0; t < 16; t++) {
        float4 h = *(float4*)&hs[t][k0];
        acc[t] += w0 * h.x + w1v * h.y + w2v * h.z + w3v * h.w;
      }
    }
    float bb = b2[tid];
#pragma unroll
    for (int t = 0; t < 16; t++) h2s[t][tid] = fmaxf(acc[t] + bb, 0.f);
  }
  __syncthreads();

  if (tid < 192) {
    int grp = tid / 96;
    int o = tid - grp * 96;
    int tb = grp * 8;
    float acc[8];
#pragma unroll
    for (int t = 0; t < 8; t++) acc[t] = 0.f;
    for (int k0 = 0; k0 < 256; k0 += 4) {
      float w0 = w3T[(k0 + 0) * 96 + o];
      float w1v = w3T[(k0 + 1) * 96 + o];
      float w2v = w3T[(k0 + 2) * 96 + o];
      float w3v = w3T[(k0 + 3) * 96 + o];
#pragma unroll
      for (int t = 0; t < 8; t++) {
        float4 h = *(float4*)&h2s[tb + t][k0];
        acc[t] += w0 * h.x + w1v * h.y + w2v * h.z + w3v * h.w;
      }
    }
    float bb = b3[o];
#pragma unroll
    for (int t = 0; t < 8; t++) rec[tb + t][o] = acc[t] + bb;
  }
#pragma unroll
  for (int s = 0; s < 6; s++) {
    int v = tid + s * 256;
    int t = v / 96, c = v - 96 * t;
    gts[t][c] = neigh[(size_t)(t0 + t) * 96 + c];
  }
  __syncthreads();

  float local = 0.f;
#pragma unroll
  for (int pp = 0; pp < 2; ++pp) {
    int p = tid + pp * 256;
    int t = p >> 5, i = p & 31;
    float rx = rec[t][3 * i], ry = rec[t][3 * i + 1], rz = rec[t][3 * i + 2];
    float gx = gts[t][3 * i], gy = gts[t][3 * i + 1], gz = gts[t][3 * i + 2];
    float mA = FLT_MAX, mB = FLT_MAX;
#pragma unroll
    for (int j = 0; j < 32; j++) {
      float dx = rx - gts[t][3 * j], dy = ry - gts[t][3 * j + 1], dz = rz - gts[t][3 * j + 2];
      float d = dx * dx + dy * dy + dz * dz;
      mA = fminf(mA, d);
      dx = rec[t][3 * j] - gx; dy = rec[t][3 * j + 1] - gy; dz = rec[t][3 * j + 2] - gz;
      d = dx * dx + dy * dy + dz * dz;
      mB = fminf(mB, d);
    }
    local += mA + mB;
  }
#pragma unroll
  for (int off = 32; off; off >>= 1) local += __shfl_down(local, off, 64);
  if ((tid & 63) == 0) wsum[tid >> 6] = local;
  __syncthreads();
  if (tid == 0) {
    float s = wsum[0] + wsum[1] + wsum[2] + wsum[3];
    atomicAdd(out, s * (1.0f / (float)(NTOK * KPTS)));
  }
}

extern "C" void kernel_launch(void* const* d_in, const int* in_sizes, int n_in,
                              void* d_out, int out_size, void* d_ws, size_t ws_size,
                              hipStream_t stream) {
  const float* pf    = (const float*)d_in[0];
  const float* neigh = (const float*)d_in[1];
  const float* cb    = (const float*)d_in[2];
  const float* w1    = (const float*)d_in[3];
  const float* b1    = (const float*)d_in[4];
  const float* w2    = (const float*)d_in[5];
  const float* b2    = (const float*)d_in[6];
  const float* w3    = (const float*)d_in[7];
  const float* b3    = (const float*)d_in[8];
  float* out = (float*)d_out;
  float* ws = (float*)d_ws;

  float* cnorm = ws;                        // 8192 f
  float* w1T   = ws + 8192;                 // 131072 f
  float* w2T   = ws + 139264;               // 131072 f
  float* w3T   = ws + 270336;               // 24576 f
  float* pv    = ws + 294912;               // 64*8192 f
  int*   pi    = (int*)(ws + 819200);       // 64*8192 i
  int*   ids   = (int*)(ws + 1343488);      // 8192 i
  ushort* ub   = (ushort*)(ws + 1351680);
  ushort* pf_hi = ub;                       // 8*8192*GAP each
  ushort* pf_lo = ub + 2621440;
  ushort* cb_hi = ub + 5242880;
  ushort* cb_lo = ub + 7864320;

  hipMemsetAsync(d_out, 0, sizeof(float), stream);
  cnorm_k<<<NCB / 4, 256, 0, stream>>>(cb, cnorm);
  cvt_k<<<2048, 256, 0, stream>>>(pf, pf_hi, pf_lo);
  cvt_k<<<2048, 256, 0, stream>>>(cb, cb_hi, cb_lo);
  transpose_k<<<512, 256, 0, stream>>>(w1, w1T, 512, 256);
  transpose_k<<<512, 256, 0, stream>>>(w2, w2T, 256, 512);
  transpose_k<<<96, 256, 0, stream>>>(w3, w3T, 96, 256);
  argmin_k<<<dim3(64, 64), 256, 0, stream>>>(pf_hi, pf_lo, cb_hi, cb_lo, cnorm, pv, pi);
  merge_k<<<NTOK / 256, 256, 0, stream>>>(pv, pi, ids);
  mlp_chamfer_k<<<NTOK / 16, 256, 0, stream>>>(cb, ids, w1T, b1, w2T, b2, w3T, b3, neigh, out);
}

// Round 3
// 321.572 us; speedup vs baseline: 3.1418x; 1.0513x over previous
//
#include <hip/hip_runtime.h>
#include <hip/hip_bf16.h>
#include <float.h>

#define NTOK 8192   // B*G tokens
#define NCB  8192   // codebook entries
#define CDIM 256
#define KPTS 32

typedef __attribute__((ext_vector_type(8))) short short8;   // 8 bf16 (4 VGPRs)
typedef __attribute__((ext_vector_type(4))) float f32x4;
typedef unsigned int u32;

__device__ __forceinline__ void gl_lds16(const ushort* g, ushort* l) {
  __builtin_amdgcn_global_load_lds(
      (const __attribute__((address_space(1))) u32*)(g),
      (__attribute__((address_space(3))) u32*)(l), 16, 0, 0);
}

__device__ __forceinline__ void bf16_split(float x, ushort& h, ushort& l) {
  u32 u = __float_as_uint(x);
  u32 hb = (u + 0x7fffu + ((u >> 16) & 1u)) & 0xffff0000u;  // RNE to bf16
  float hf = __uint_as_float(hb);
  float lf = x - hf;
  u32 ul = __float_as_uint(lf);
  u32 lb = ul + 0x7fffu + ((ul >> 16) & 1u);
  h = (ushort)(hb >> 16);
  l = (ushort)(lb >> 16);
}

// ---------------- cnorm: |c_n|^2 (fp32 exact) ----------------
__global__ __launch_bounds__(256) void cnorm_k(const float* __restrict__ cb,
                                               float* __restrict__ cnorm) {
  int wave = threadIdx.x >> 6, lane = threadIdx.x & 63;
  int row = blockIdx.x * 4 + wave;
  const float4* r = (const float4*)(cb + (size_t)row * CDIM);
  float4 v = r[lane];
  float s = v.x * v.x + v.y * v.y + v.z * v.z + v.w * v.w;
#pragma unroll
  for (int off = 32; off; off >>= 1) s += __shfl_down(s, off, 64);
  if (lane == 0) cnorm[row] = s;
}

// ---- fp32 [R][K] row-major (opt. gathered) -> split hi/lo in MFMA
// fragment order: [tile=row>>4][kb=k>>5][lane=((k>>3)&3)*16 + (row&15)][k&7]
__global__ __launch_bounds__(256) void split_swizzle_k(
    const float* __restrict__ src, const int* __restrict__ ids,
    int R, int KB, ushort* __restrict__ hi, ushort* __restrict__ lo) {
  int tile = blockIdx.x * 4 + (threadIdx.x >> 6);
  if (tile >= (R >> 4)) return;
  int lane = threadIdx.x & 63;
  int r16 = lane & 15, quad = lane >> 4;
  int row = tile * 16 + r16;
  int srow = ids ? ids[row] : row;
  int K = KB * 32;
  const float* sp = src + (size_t)srow * K + quad * 8;
  for (int kb = 0; kb < KB; ++kb) {
    float4 a = *(const float4*)(sp + kb * 32);
    float4 b = *(const float4*)(sp + kb * 32 + 4);
    float x[8] = {a.x, a.y, a.z, a.w, b.x, b.y, b.z, b.w};
    ushort h[8], l[8];
#pragma unroll
    for (int e = 0; e < 8; e++) bf16_split(x[e], h[e], l[e]);
    size_t o = ((size_t)tile * KB + kb) * 512 + lane * 8;
    *(ushort4*)(hi + o)     = make_ushort4(h[0], h[1], h[2], h[3]);
    *(ushort4*)(hi + o + 4) = make_ushort4(h[4], h[5], h[6], h[7]);
    *(ushort4*)(lo + o)     = make_ushort4(l[0], l[1], l[2], l[3]);
    *(ushort4*)(lo + o + 4) = make_ushort4(l[4], l[5], l[6], l[7]);
  }
}

// -------- fused MFMA distance GEMM + per-tile argmin --------
// d = |c|^2 - 2 p.c ; p.c via split bf16: ah*bh + ah*bl + al*bh
__global__ __launch_bounds__(256, 2) void argmin_k(
    const ushort* __restrict__ Ahg, const ushort* __restrict__ Alg,
    const ushort* __restrict__ Bhg, const ushort* __restrict__ Blg,
    const float* __restrict__ cnorm,
    float* __restrict__ pv, int* __restrict__ pi) {
  __shared__ ushort lds[32 * 512];   // 32 KiB: [Ah 8][Al 8][Bh 8][Bl 8] x 1KB
  int tid = threadIdx.x;
  int nt = blockIdx.x, mt = blockIdx.y;
  int wv = tid >> 6, lane = tid & 63;
  int quad = lane >> 4, r16 = lane & 15;
  int wr = wv >> 1, wc = wv & 1;

  f32x4 acc[4][4];
#pragma unroll
  for (int i = 0; i < 4; i++)
#pragma unroll
    for (int j = 0; j < 4; j++) acc[i][j] = (f32x4){0.f, 0.f, 0.f, 0.f};

  for (int kb = 0; kb < 8; ++kb) {
#pragma unroll
    for (int u = 0; u < 8; ++u) {
      int c = wv + u * 4;
      int arr = c >> 3, t = c & 7;
      const ushort* base = (arr == 0) ? Ahg : (arr == 1) ? Alg : (arr == 2) ? Bhg : Blg;
      int gt = ((arr < 2) ? mt : nt) * 8 + t;
      gl_lds16(base + ((size_t)gt * 8 + kb) * 512 + lane * 8, lds + c * 512);
    }
    __syncthreads();
    short8 fah[4], fal[4], fbh[4], fbl[4];
#pragma unroll
    for (int i = 0; i < 4; i++) {
      fah[i] = *(const short8*)(lds + (wr * 4 + i) * 512 + lane * 8);
      fal[i] = *(const short8*)(lds + (8 + wr * 4 + i) * 512 + lane * 8);
    }
#pragma unroll
    for (int j = 0; j < 4; j++) {
      fbh[j] = *(const short8*)(lds + (16 + wc * 4 + j) * 512 + lane * 8);
      fbl[j] = *(const short8*)(lds + (24 + wc * 4 + j) * 512 + lane * 8);
    }
#pragma unroll
    for (int i = 0; i < 4; i++)
#pragma unroll
      for (int j = 0; j < 4; j++) {
        acc[i][j] = __builtin_amdgcn_mfma_f32_16x16x32_bf16(fah[i], fbh[j], acc[i][j], 0, 0, 0);
        acc[i][j] = __builtin_amdgcn_mfma_f32_16x16x32_bf16(fah[i], fbl[j], acc[i][j], 0, 0, 0);
        acc[i][j] = __builtin_amdgcn_mfma_f32_16x16x32_bf16(fal[i], fbh[j], acc[i][j], 0, 0, 0);
      }
    __syncthreads();
  }

  // epilogue: per-row argmin; C/D layout col=r16, row=quad*4+reg
#pragma unroll
  for (int i = 0; i < 4; i++) {
    float bv[4];
    int bi[4];
#pragma unroll
    for (int reg = 0; reg < 4; reg++) { bv[reg] = FLT_MAX; bi[reg] = 0x7fffffff; }
#pragma unroll
    for (int j = 0; j < 4; j++) {
      int col = nt * 128 + wc * 64 + j * 16 + r16;
      float cn = cnorm[col];
#pragma unroll
      for (int reg = 0; reg < 4; reg++) {
        float d = cn - 2.f * acc[i][j][reg];
        if (d < bv[reg] || (d == bv[reg] && col < bi[reg])) { bv[reg] = d; bi[reg] = col; }
      }
    }
#pragma unroll
    for (int m = 1; m < 16; m <<= 1) {
#pragma unroll
      for (int reg = 0; reg < 4; reg++) {
        float ov = __shfl_xor(bv[reg], m, 64);
        int oi = __shfl_xor(bi[reg], m, 64);
        if (ov < bv[reg] || (ov == bv[reg] && oi < bi[reg])) { bv[reg] = ov; bi[reg] = oi; }
      }
    }
    if (r16 == 0) {
#pragma unroll
      for (int reg = 0; reg < 4; reg++) {
        int row = mt * 128 + wr * 64 + i * 16 + quad * 4 + reg;
        pv[(size_t)nt * NTOK + row] = bv[reg];
        pi[(size_t)nt * NTOK + row] = bi[reg];
      }
    }
  }
}

// ---------------- merge 64 N-tiles ----------------
__global__ __launch_bounds__(256) void merge_k(const float* __restrict__ pv,
                                               const int* __restrict__ pi,
                                               int* __restrict__ ids) {
  int t = blockIdx.x * 256 + threadIdx.x;
  float bv = FLT_MAX;
  int bi = 0x7fffffff;
#pragma unroll 8
  for (int s = 0; s < 64; s++) {
    float v = pv[(size_t)s * NTOK + t];
    int ii = pi[(size_t)s * NTOK + t];
    if (v < bv || (v == bv && ii < bi)) { bv = v; bi = ii; }
  }
  ids[t] = bi;
}

// -------- generic split-bf16 MFMA GEMM: C = A * B^T + bias [, relu] --------
// A: [M rows][K] split-swizzled; B: [N rows][K] split-swizzled.
// OUTF32=0: write C split-swizzled (ostride = N/32) for next layer's A.
// OUTF32=1: write C fp32 row-major (ostride = N).
template <int BM, int BN, int KB, bool RELU, int OUTF32>
__global__ __launch_bounds__(256, 2) void gemm_k(
    const ushort* __restrict__ Ahg, const ushort* __restrict__ Alg,
    const ushort* __restrict__ Bhg, const ushort* __restrict__ Blg,
    const float* __restrict__ bias, int ostride,
    ushort* __restrict__ oh, ushort* __restrict__ ol, float* __restrict__ of) {
  constexpr int NC = (BM + BN) * 2;
  constexpr int WM = BM / 2, WN = BN / 2;
  __shared__ ushort lds[NC * 512];
  int tid = threadIdx.x;
  int ntB = blockIdx.x, mtB = blockIdx.y;
  int wv = tid >> 6, lane = tid & 63;
  int quad = lane >> 4, r16 = lane & 15;
  int wr = wv >> 1, wc = wv & 1;

  f32x4 acc[WM][WN];
#pragma unroll
  for (int i = 0; i < WM; i++)
#pragma unroll
    for (int j = 0; j < WN; j++) acc[i][j] = (f32x4){0.f, 0.f, 0.f, 0.f};

  for (int kb = 0; kb < KB; ++kb) {
    for (int c = wv; c < NC; c += 4) {
      const ushort* base;
      int gt;
      if (c < BM)              { base = Ahg; gt = mtB * BM + c; }
      else if (c < 2 * BM)     { base = Alg; gt = mtB * BM + (c - BM); }
      else if (c < 2 * BM + BN){ base = Bhg; gt = ntB * BN + (c - 2 * BM); }
      else                     { base = Blg; gt = ntB * BN + (c - 2 * BM - BN); }
      gl_lds16(base + ((size_t)gt * KB + kb) * 512 + lane * 8, lds + c * 512);
    }
    __syncthreads();
    short8 fah[WM], fal[WM], fbh[WN], fbl[WN];
#pragma unroll
    for (int i = 0; i < WM; i++) {
      fah[i] = *(const short8*)(lds + (wr * WM + i) * 512 + lane * 8);
      fal[i] = *(const short8*)(lds + (BM + wr * WM + i) * 512 + lane * 8);
    }
#pragma unroll
    for (int j = 0; j < WN; j++) {
      fbh[j] = *(const short8*)(lds + (2 * BM + wc * WN + j) * 512 + lane * 8);
      fbl[j] = *(const short8*)(lds + (2 * BM + BN + wc * WN + j) * 512 + lane * 8);
    }
#pragma unroll
    for (int i = 0; i < WM; i++)
#pragma unroll
      for (int j = 0; j < WN; j++) {
        acc[i][j] = __builtin_amdgcn_mfma_f32_16x16x32_bf16(fah[i], fbh[j], acc[i][j], 0, 0, 0);
        acc[i][j] = __builtin_amdgcn_mfma_f32_16x16x32_bf16(fah[i], fbl[j], acc[i][j], 0, 0, 0);
        acc[i][j] = __builtin_amdgcn_mfma_f32_16x16x32_bf16(fal[i], fbh[j], acc[i][j], 0, 0, 0);
      }
    __syncthreads();
  }

  // epilogue
  float bj[WN];
  int colj[WN];
#pragma unroll
  for (int j = 0; j < WN; j++) {
    colj[j] = ntB * BN * 16 + (wc * WN + j) * 16 + r16;
    bj[j] = bias[colj[j]];
  }
#pragma unroll
  for (int i = 0; i < WM; i++) {
#pragma unroll
    for (int j = 0; j < WN; j++) {
#pragma unroll
      for (int reg = 0; reg < 4; reg++) {
        int row = mtB * BM * 16 + (wr * WM + i) * 16 + quad * 4 + reg;
        float v = acc[i][j][reg] + bj[j];
        if (RELU) v = fmaxf(v, 0.f);
        int col = colj[j];
        if (OUTF32) {
          of[(size_t)row * ostride + col] = v;
        } else {
          ushort h, l;
          bf16_split(v, h, l);
          size_t o = ((size_t)(row >> 4) * ostride + (col >> 5)) * 512 +
                     (((col >> 3) & 3) * 16 + (row & 15)) * 8 + (col & 7);
          oh[o] = h;
          ol[o] = l;
        }
      }
    }
  }
}

// ---------------- chamfer over rec[8192][96] fp32 ----------------
__global__ __launch_bounds__(256) void chamfer_k(const float* __restrict__ rec_g,
                                                 const float* __restrict__ neigh,
                                                 float* __restrict__ out) {
  __shared__ float rec[16][96];
  __shared__ float gts[16][96];
  __shared__ float wsum[4];
  int tid = threadIdx.x;
  int t0 = blockIdx.x * 16;
#pragma unroll
  for (int s = 0; s < 6; s++) {
    int v = tid + s * 256;
    int t = v / 96, c = v - 96 * t;
    rec[t][c] = rec_g[(size_t)(t0 + t) * 96 + c];
    gts[t][c] = neigh[(size_t)(t0 + t) * 96 + c];
  }
  __syncthreads();
  float local = 0.f;
#pragma unroll
  for (int pp = 0; pp < 2; ++pp) {
    int p = tid + pp * 256;
    int t = p >> 5, i = p & 31;
    float rx = rec[t][3 * i], ry = rec[t][3 * i + 1], rz = rec[t][3 * i + 2];
    float gx = gts[t][3 * i], gy = gts[t][3 * i + 1], gz = gts[t][3 * i + 2];
    float mA = FLT_MAX, mB = FLT_MAX;
#pragma unroll
    for (int j = 0; j < 32; j++) {
      float dx = rx - gts[t][3 * j], dy = ry - gts[t][3 * j + 1], dz = rz - gts[t][3 * j + 2];
      float d = dx * dx + dy * dy + dz * dz;
      mA = fminf(mA, d);
      dx = rec[t][3 * j] - gx; dy = rec[t][3 * j + 1] - gy; dz = rec[t][3 * j + 2] - gz;
      d = dx * dx + dy * dy + dz * dz;
      mB = fminf(mB, d);
    }
    local += mA + mB;
  }
#pragma unroll
  for (int off = 32; off; off >>= 1) local += __shfl_down(local, off, 64);
  if ((tid & 63) == 0) wsum[tid >> 6] = local;
  __syncthreads();
  if (tid == 0) {
    float s = wsum[0] + wsum[1] + wsum[2] + wsum[3];
    atomicAdd(out, s * (1.0f / (float)(NTOK * KPTS)));
  }
}

extern "C" void kernel_launch(void* const* d_in, const int* in_sizes, int n_in,
                              void* d_out, int out_size, void* d_ws, size_t ws_size,
                              hipStream_t stream) {
  const float* pf    = (const float*)d_in[0];
  const float* neigh = (const float*)d_in[1];
  const float* cb    = (const float*)d_in[2];
  const float* w1    = (const float*)d_in[3];
  const float* b1    = (const float*)d_in[4];
  const float* w2    = (const float*)d_in[5];
  const float* b2    = (const float*)d_in[6];
  const float* w3    = (const float*)d_in[7];
  const float* b3    = (const float*)d_in[8];
  float* out = (float*)d_out;
  float* ws = (float*)d_ws;

  float* cnorm = ws;                          // 8192
  int*   ids   = (int*)(ws + 8192);           // 8192
  float* pv    = ws + 16384;                  // 64*8192
  int*   pi    = (int*)(ws + 540672);         // 64*8192
  float* rec   = ws + 1064960;                // 8192*96
  ushort* ub = (ushort*)(ws + 1851392);
  ushort* w1s_hi = ub;                        // 512*256
  ushort* w1s_lo = ub + 131072;
  ushort* w2s_hi = ub + 262144;               // 256*512
  ushort* w2s_lo = ub + 393216;
  ushort* w3s_hi = ub + 524288;               // 96*256
  ushort* w3s_lo = ub + 548864;
  ushort* quant_hi = ub + 573440;             // 8192*256
  ushort* quant_lo = ub + 2670592;
  ushort* h2_hi = ub + 4767744;               // 8192*256
  ushort* h2_lo = ub + 6864896;
  ushort* pf_hi = ub + 8962048;               // 8192*256
  ushort* pf_lo = ub + 11059200;
  ushort* cb_hi = ub + 13156352;
  ushort* cb_lo = ub + 15253504;
  // h1 (8192*512) aliases pf/cb splits (dead after argmin)
  ushort* h1_hi = pf_hi;
  ushort* h1_lo = cb_hi;

  hipMemsetAsync(d_out, 0, sizeof(float), stream);
  cnorm_k<<<NCB / 4, 256, 0, stream>>>(cb, cnorm);
  split_swizzle_k<<<128, 256, 0, stream>>>(pf, nullptr, 8192, 8, pf_hi, pf_lo);
  split_swizzle_k<<<128, 256, 0, stream>>>(cb, nullptr, 8192, 8, cb_hi, cb_lo);
  split_swizzle_k<<<8, 256, 0, stream>>>(w1, nullptr, 512, 8, w1s_hi, w1s_lo);
  split_swizzle_k<<<4, 256, 0, stream>>>(w2, nullptr, 256, 16, w2s_hi, w2s_lo);
  split_swizzle_k<<<2, 256, 0, stream>>>(w3, nullptr, 96, 8, w3s_hi, w3s_lo);
  argmin_k<<<dim3(64, 64), 256, 0, stream>>>(pf_hi, pf_lo, cb_hi, cb_lo, cnorm, pv, pi);
  merge_k<<<NTOK / 256, 256, 0, stream>>>(pv, pi, ids);
  split_swizzle_k<<<128, 256, 0, stream>>>(cb, ids, 8192, 8, quant_hi, quant_lo);
  gemm_k<8, 8, 8, true, 0><<<dim3(4, 64), 256, 0, stream>>>(
      quant_hi, quant_lo, w1s_hi, w1s_lo, b1, 16, h1_hi, h1_lo, nullptr);
  gemm_k<8, 4, 16, true, 0><<<dim3(4, 64), 256, 0, stream>>>(
      h1_hi, h1_lo, w2s_hi, w2s_lo, b2, 8, h2_hi, h2_lo, nullptr);
  gemm_k<4, 6, 8, false, 1><<<dim3(1, 128), 256, 0, stream>>>(
      h2_hi, h2_lo, w3s_hi, w3s_lo, b3, 96, nullptr, nullptr, rec);
  chamfer_k<<<NTOK / 16, 256, 0, stream>>>(rec, neigh, out);
}

// Round 4
// 272.679 us; speedup vs baseline: 3.7051x; 1.1793x over previous
//
#include <hip/hip_runtime.h>
#include <hip/hip_bf16.h>
#include <float.h>

#define NTOK 8192   // B*G tokens
#define NCB  8192   // codebook entries
#define CDIM 256
#define KPTS 32

typedef __attribute__((ext_vector_type(8))) short short8;   // 8 bf16 (4 VGPRs)
typedef __attribute__((ext_vector_type(4))) float f32x4;
typedef unsigned int u32;
typedef unsigned long long u64;

__device__ __forceinline__ void gl_lds16(const ushort* g, ushort* l) {
  __builtin_amdgcn_global_load_lds(
      (const __attribute__((address_space(1))) u32*)(g),
      (__attribute__((address_space(3))) u32*)(l), 16, 0, 0);
}

__device__ __forceinline__ void bf16_split(float x, ushort& h, ushort& l) {
  u32 u = __float_as_uint(x);
  u32 hb = (u + 0x7fffu + ((u >> 16) & 1u)) & 0xffff0000u;  // RNE to bf16
  float hf = __uint_as_float(hb);
  float lf = x - hf;
  u32 ul = __float_as_uint(lf);
  u32 lb = ul + 0x7fffu + ((ul >> 16) & 1u);
  h = (ushort)(hb >> 16);
  l = (ushort)(lb >> 16);
}

__device__ __forceinline__ ushort bf16_rne(float x) {
  u32 u = __float_as_uint(x);
  return (ushort)((u + 0x7fffu + ((u >> 16) & 1u)) >> 16);
}

// ---- pf + cb -> split hi/lo fragment-order; cb waves also accumulate |c|^2 ----
// fragment order: [tile=row>>4][kb=k>>5][lane=((k>>3)&3)*16 + (row&15)][k&7]
// one wave per (array, tile, kb): 8192 wave-tasks, 2048 blocks
__global__ __launch_bounds__(256) void ss_data_k(
    const float* __restrict__ pf, const float* __restrict__ cb,
    ushort* __restrict__ pf_hi, ushort* __restrict__ pf_lo,
    ushort* __restrict__ cb_hi, ushort* __restrict__ cb_lo,
    float* __restrict__ cnorm) {
  int gid = blockIdx.x * 4 + (threadIdx.x >> 6);
  int lane = threadIdx.x & 63, r16 = lane & 15, quad = lane >> 4;
  bool is_cb = gid >= 4096;
  int t = is_cb ? gid - 4096 : gid;
  int tile = t >> 3, kb = t & 7;
  const float* src = is_cb ? cb : pf;
  int row = tile * 16 + r16;
  const float* sp = src + (size_t)row * CDIM + kb * 32 + quad * 8;
  float4 a = *(const float4*)sp;
  float4 b = *(const float4*)(sp + 4);
  float x[8] = {a.x, a.y, a.z, a.w, b.x, b.y, b.z, b.w};
  ushort h[8], l[8];
#pragma unroll
  for (int e = 0; e < 8; e++) bf16_split(x[e], h[e], l[e]);
  size_t o = ((size_t)tile * 8 + kb) * 512 + lane * 8;
  short8 vh = {(short)h[0], (short)h[1], (short)h[2], (short)h[3],
               (short)h[4], (short)h[5], (short)h[6], (short)h[7]};
  short8 vl = {(short)l[0], (short)l[1], (short)l[2], (short)l[3],
               (short)l[4], (short)l[5], (short)l[6], (short)l[7]};
  *(short8*)((is_cb ? cb_hi : pf_hi) + o) = vh;
  *(short8*)((is_cb ? cb_lo : pf_lo) + o) = vl;
  if (is_cb) {
    float s = 0.f;
#pragma unroll
    for (int e = 0; e < 8; e++) s += x[e] * x[e];
    s += __shfl_xor(s, 16, 64);
    s += __shfl_xor(s, 32, 64);
    if (quad == 0) atomicAdd(cnorm + row, s);
  }
}

// ---- all three weight matrices -> single-bf16 fragment order ----
// tasks: w1 (32 tiles x 8 kb = 256), w2 (16 x 16 = 256), w3 (6 x 8 = 48)
__global__ __launch_bounds__(256) void ss_w_k(
    const float* __restrict__ w1, const float* __restrict__ w2,
    const float* __restrict__ w3, ushort* __restrict__ w1s,
    ushort* __restrict__ w2s, ushort* __restrict__ w3s) {
  int gid = blockIdx.x * 4 + (threadIdx.x >> 6);
  if (gid >= 560) return;
  int lane = threadIdx.x & 63, r16 = lane & 15, quad = lane >> 4;
  const float* src;
  ushort* dst;
  int t, KB;
  if (gid < 256)      { src = w1; dst = w1s; KB = 8;  t = gid; }
  else if (gid < 512) { src = w2; dst = w2s; KB = 16; t = gid - 256; }
  else                { src = w3; dst = w3s; KB = 8;  t = gid - 512; }
  int tile = t / KB, kb = t - tile * KB, K = KB * 32;
  int row = tile * 16 + r16;
  const float* sp = src + (size_t)row * K + kb * 32 + quad * 8;
  float4 a = *(const float4*)sp;
  float4 b = *(const float4*)(sp + 4);
  float x[8] = {a.x, a.y, a.z, a.w, b.x, b.y, b.z, b.w};
  short8 vh = {(short)bf16_rne(x[0]), (short)bf16_rne(x[1]),
               (short)bf16_rne(x[2]), (short)bf16_rne(x[3]),
               (short)bf16_rne(x[4]), (short)bf16_rne(x[5]),
               (short)bf16_rne(x[6]), (short)bf16_rne(x[7])};
  *(short8*)(dst + ((size_t)tile * KB + kb) * 512 + lane * 8) = vh;
}

// -------- fused MFMA distance GEMM + argmin via packed u64 atomicMin --------
// d = |c|^2 - 2 p.c ; p.c via split bf16: ah*bh + ah*bl + al*bh
__global__ __launch_bounds__(256, 2) void argmin_k(
    const ushort* __restrict__ Ahg, const ushort* __restrict__ Alg,
    const ushort* __restrict__ Bhg, const ushort* __restrict__ Blg,
    const float* __restrict__ cnorm, u64* __restrict__ keys) {
  __shared__ ushort lds[32 * 512];   // 32 KiB
  int tid = threadIdx.x;
  int nt = blockIdx.x, mt = blockIdx.y;
  int wv = tid >> 6, lane = tid & 63;
  int quad = lane >> 4, r16 = lane & 15;
  int wr = wv >> 1, wc = wv & 1;

  f32x4 acc[4][4];
#pragma unroll
  for (int i = 0; i < 4; i++)
#pragma unroll
    for (int j = 0; j < 4; j++) acc[i][j] = (f32x4){0.f, 0.f, 0.f, 0.f};

  for (int kb = 0; kb < 8; ++kb) {
#pragma unroll
    for (int u = 0; u < 8; ++u) {
      int c = wv + u * 4;
      int arr = c >> 3, t = c & 7;
      const ushort* base = (arr == 0) ? Ahg : (arr == 1) ? Alg : (arr == 2) ? Bhg : Blg;
      int gt = ((arr < 2) ? mt : nt) * 8 + t;
      gl_lds16(base + ((size_t)gt * 8 + kb) * 512 + lane * 8, lds + c * 512);
    }
    __syncthreads();
    short8 fah[4], fal[4], fbh[4], fbl[4];
#pragma unroll
    for (int i = 0; i < 4; i++) {
      fah[i] = *(const short8*)(lds + (wr * 4 + i) * 512 + lane * 8);
      fal[i] = *(const short8*)(lds + (8 + wr * 4 + i) * 512 + lane * 8);
    }
#pragma unroll
    for (int j = 0; j < 4; j++) {
      fbh[j] = *(const short8*)(lds + (16 + wc * 4 + j) * 512 + lane * 8);
      fbl[j] = *(const short8*)(lds + (24 + wc * 4 + j) * 512 + lane * 8);
    }
#pragma unroll
    for (int i = 0; i < 4; i++)
#pragma unroll
      for (int j = 0; j < 4; j++) {
        acc[i][j] = __builtin_amdgcn_mfma_f32_16x16x32_bf16(fah[i], fbh[j], acc[i][j], 0, 0, 0);
        acc[i][j] = __builtin_amdgcn_mfma_f32_16x16x32_bf16(fah[i], fbl[j], acc[i][j], 0, 0, 0);
        acc[i][j] = __builtin_amdgcn_mfma_f32_16x16x32_bf16(fal[i], fbh[j], acc[i][j], 0, 0, 0);
      }
    __syncthreads();
  }

  // epilogue: per-row argmin over this block's 128 cols, then atomicMin
#pragma unroll
  for (int i = 0; i < 4; i++) {
    float bv[4];
    int bi[4];
#pragma unroll
    for (int reg = 0; reg < 4; reg++) { bv[reg] = FLT_MAX; bi[reg] = 0x7fffffff; }
#pragma unroll
    for (int j = 0; j < 4; j++) {
      int col = nt * 128 + wc * 64 + j * 16 + r16;
      float cn = cnorm[col];
#pragma unroll
      for (int reg = 0; reg < 4; reg++) {
        float d = cn - 2.f * acc[i][j][reg];
        if (d < bv[reg] || (d == bv[reg] && col < bi[reg])) { bv[reg] = d; bi[reg] = col; }
      }
    }
#pragma unroll
    for (int m = 1; m < 16; m <<= 1) {
#pragma unroll
      for (int reg = 0; reg < 4; reg++) {
        float ov = __shfl_xor(bv[reg], m, 64);
        int oi = __shfl_xor(bi[reg], m, 64);
        if (ov < bv[reg] || (ov == bv[reg] && oi < bi[reg])) { bv[reg] = ov; bi[reg] = oi; }
      }
    }
    if (r16 == 0) {
#pragma unroll
      for (int reg = 0; reg < 4; reg++) {
        int row = mt * 128 + wr * 64 + i * 16 + quad * 4 + reg;
        u32 u = __float_as_uint(bv[reg]);
        u32 mk = (u & 0x80000000u) ? ~u : (u | 0x80000000u);  // monotone map
        atomicMin(keys + row, ((u64)mk << 32) | (u32)bi[reg]);
      }
    }
  }
}

// ---- gather quantized rows directly from cb_hi fragments (RNE(x) == hi) ----
// one wave per (tile, kb): 4096 tasks, 1024 blocks
__global__ __launch_bounds__(256) void gather_k(const u64* __restrict__ keys,
                                                const ushort* __restrict__ cb_hi,
                                                ushort* __restrict__ quant) {
  int gid = blockIdx.x * 4 + (threadIdx.x >> 6);
  int lane = threadIdx.x & 63, r16 = lane & 15, quad = lane >> 4;
  int tile = gid >> 3, kb = gid & 7;
  int row = tile * 16 + r16;
  int id = (int)((const u32*)keys)[2 * row];   // low word of packed key
  short8 v = *(const short8*)(cb_hi + ((size_t)(id >> 4) * 8 + kb) * 512 +
                              (size_t)((id & 15) + quad * 16) * 8);
  *(short8*)(quant + ((size_t)tile * 8 + kb) * 512 + lane * 8) = v;
}

// -------- single-bf16 MFMA GEMM: C = A * B^T + bias [, relu] --------
// out: bf16 fragment order with okb = N/32 k-blocks per row-tile
template <int BM, int BN, int KB, bool RELU>
__global__ __launch_bounds__(256, 2) void gemm_bf_k(
    const ushort* __restrict__ Ag, const ushort* __restrict__ Bg,
    const float* __restrict__ bias, int okb, ushort* __restrict__ obf) {
  constexpr int NC = BM + BN;
  constexpr int WM = BM / 2, WN = BN / 2;
  __shared__ ushort lds[NC * 512];
  int tid = threadIdx.x;
  int ntB = blockIdx.x, mtB = blockIdx.y;
  int wv = tid >> 6, lane = tid & 63;
  int quad = lane >> 4, r16 = lane & 15;
  int wr = wv >> 1, wc = wv & 1;

  f32x4 acc[WM][WN];
#pragma unroll
  for (int i = 0; i < WM; i++)
#pragma unroll
    for (int j = 0; j < WN; j++) acc[i][j] = (f32x4){0.f, 0.f, 0.f, 0.f};

  for (int kb = 0; kb < KB; ++kb) {
    for (int c = wv; c < NC; c += 4) {
      const ushort* base;
      int gt;
      if (c < BM) { base = Ag; gt = mtB * BM + c; }
      else        { base = Bg; gt = ntB * BN + (c - BM); }
      gl_lds16(base + ((size_t)gt * KB + kb) * 512 + lane * 8, lds + c * 512);
    }
    __syncthreads();
    short8 fa[WM], fb[WN];
#pragma unroll
    for (int i = 0; i < WM; i++)
      fa[i] = *(const short8*)(lds + (wr * WM + i) * 512 + lane * 8);
#pragma unroll
    for (int j = 0; j < WN; j++)
      fb[j] = *(const short8*)(lds + (BM + wc * WN + j) * 512 + lane * 8);
#pragma unroll
    for (int i = 0; i < WM; i++)
#pragma unroll
      for (int j = 0; j < WN; j++)
        acc[i][j] = __builtin_amdgcn_mfma_f32_16x16x32_bf16(fa[i], fb[j], acc[i][j], 0, 0, 0);
    __syncthreads();
  }

  // epilogue: bias + relu + rne + fragment-order store
#pragma unroll
  for (int j = 0; j < WN; j++) {
    int col = ntB * BN * 16 + (wc * WN + j) * 16 + r16;
    float bj = bias[col];
#pragma unroll
    for (int i = 0; i < WM; i++) {
#pragma unroll
      for (int reg = 0; reg < 4; reg++) {
        int row = mtB * BM * 16 + (wr * WM + i) * 16 + quad * 4 + reg;
        float v = acc[i][j][reg] + bj;
        if (RELU) v = fmaxf(v, 0.f);
        size_t o = ((size_t)(row >> 4) * okb + (col >> 5)) * 512 +
                   (size_t)(((col >> 3) & 3) * 16 + (row & 15)) * 8 + (col & 7);
        obf[o] = bf16_rne(v);
      }
    }
  }
}

// -------- layer-3 GEMM (64 tokens x 96 outs per block) fused with chamfer ----
__global__ __launch_bounds__(256) void gemm3_chamfer_k(
    const ushort* __restrict__ Ag, const ushort* __restrict__ Bg,
    const float* __restrict__ bias, const float* __restrict__ neigh,
    float* __restrict__ out) {
  constexpr int BM = 4, BN = 6, KB = 8, WM = 2, WN = 3, NC = 10;
  __shared__ ushort lds[NC * 512];
  __shared__ float rec[64][96];
  __shared__ float gts[64][96];
  __shared__ float wsum[4];
  int tid = threadIdx.x;
  int mtB = blockIdx.x;
  int wv = tid >> 6, lane = tid & 63;
  int quad = lane >> 4, r16 = lane & 15;
  int wr = wv >> 1, wc = wv & 1;

  f32x4 acc[WM][WN];
#pragma unroll
  for (int i = 0; i < WM; i++)
#pragma unroll
    for (int j = 0; j < WN; j++) acc[i][j] = (f32x4){0.f, 0.f, 0.f, 0.f};

  for (int kb = 0; kb < KB; ++kb) {
    for (int c = wv; c < NC; c += 4) {
      const ushort* base;
      int gt;
      if (c < BM) { base = Ag; gt = mtB * BM + c; }
      else        { base = Bg; gt = c - BM; }
      gl_lds16(base + ((size_t)gt * KB + kb) * 512 + lane * 8, lds + c * 512);
    }
    __syncthreads();
    short8 fa[WM], fb[WN];
#pragma unroll
    for (int i = 0; i < WM; i++)
      fa[i] = *(const short8*)(lds + (wr * WM + i) * 512 + lane * 8);
#pragma unroll
    for (int j = 0; j < WN; j++)
      fb[j] = *(const short8*)(lds + (BM + wc * WN + j) * 512 + lane * 8);
#pragma unroll
    for (int i = 0; i < WM; i++)
#pragma unroll
      for (int j = 0; j < WN; j++)
        acc[i][j] = __builtin_amdgcn_mfma_f32_16x16x32_bf16(fa[i], fb[j], acc[i][j], 0, 0, 0);
    __syncthreads();
  }

  // epilogue -> rec in LDS
#pragma unroll
  for (int j = 0; j < WN; j++) {
    int col = (wc * WN + j) * 16 + r16;
    float bj = bias[col];
#pragma unroll
    for (int i = 0; i < WM; i++) {
#pragma unroll
      for (int reg = 0; reg < 4; reg++) {
        int rl = (wr * WM + i) * 16 + quad * 4 + reg;
        rec[rl][col] = acc[i][j][reg] + bj;
      }
    }
  }
  // stage ground truth: 64 tokens x 96 floats = 1536 float4s
#pragma unroll
  for (int s = 0; s < 6; s++) {
    int idx = tid + s * 256;
    int t = idx / 24, c = (idx - t * 24) * 4;
    *(float4*)&gts[t][c] = *(const float4*)(neigh + (size_t)(mtB * 64 + t) * 96 + c);
  }
  __syncthreads();

  float local = 0.f;
#pragma unroll
  for (int pp = 0; pp < 8; ++pp) {
    int p = tid + pp * 256;
    int t = p >> 5, i = p & 31;
    float rx = rec[t][3 * i], ry = rec[t][3 * i + 1], rz = rec[t][3 * i + 2];
    float gx = gts[t][3 * i], gy = gts[t][3 * i + 1], gz = gts[t][3 * i + 2];
    float mA = FLT_MAX, mB = FLT_MAX;
#pragma unroll
    for (int j = 0; j < 32; j++) {
      float dx = rx - gts[t][3 * j], dy = ry - gts[t][3 * j + 1], dz = rz - gts[t][3 * j + 2];
      float d = dx * dx + dy * dy + dz * dz;
      mA = fminf(mA, d);
      dx = rec[t][3 * j] - gx; dy = rec[t][3 * j + 1] - gy; dz = rec[t][3 * j + 2] - gz;
      d = dx * dx + dy * dy + dz * dz;
      mB = fminf(mB, d);
    }
    local += mA + mB;
  }
#pragma unroll
  for (int off = 32; off; off >>= 1) local += __shfl_down(local, off, 64);
  if ((tid & 63) == 0) wsum[tid >> 6] = local;
  __syncthreads();
  if (tid == 0) {
    float s = wsum[0] + wsum[1] + wsum[2] + wsum[3];
    atomicAdd(out, s * (1.0f / (float)(NTOK * KPTS)));
  }
}

extern "C" void kernel_launch(void* const* d_in, const int* in_sizes, int n_in,
                              void* d_out, int out_size, void* d_ws, size_t ws_size,
                              hipStream_t stream) {
  const float* pf    = (const float*)d_in[0];
  const float* neigh = (const float*)d_in[1];
  const float* cb    = (const float*)d_in[2];
  const float* w1    = (const float*)d_in[3];
  const float* b1    = (const float*)d_in[4];
  const float* w2    = (const float*)d_in[5];
  const float* b2    = (const float*)d_in[6];
  const float* w3    = (const float*)d_in[7];
  const float* b3    = (const float*)d_in[8];
  float* out = (float*)d_out;
  float* ws = (float*)d_ws;

  u64*   keys  = (u64*)ws;                     // 8192 u64 = 64 KiB
  float* cnorm = ws + 16384;                   // 8192 f
  ushort* ub   = (ushort*)(ws + 24576);
  ushort* pf_hi = ub;                          // 8192*256 each
  ushort* pf_lo = ub + 2097152;
  ushort* cb_hi = ub + 4194304;
  ushort* cb_lo = ub + 6291456;
  ushort* quant = ub + 8388608;                // 8192*256
  ushort* h1    = ub + 10485760;               // 8192*512
  ushort* h2    = ub + 14680064;               // 8192*256
  ushort* w1s   = ub + 16777216;               // 512*256
  ushort* w2s   = ub + 16908288;               // 256*512
  ushort* w3s   = ub + 17039360;               // 96*256

  hipMemsetAsync(d_out, 0, sizeof(float), stream);
  hipMemsetAsync(keys, 0xFF, NTOK * sizeof(u64), stream);
  hipMemsetAsync(cnorm, 0, NCB * sizeof(float), stream);
  ss_data_k<<<2048, 256, 0, stream>>>(pf, cb, pf_hi, pf_lo, cb_hi, cb_lo, cnorm);
  ss_w_k<<<140, 256, 0, stream>>>(w1, w2, w3, w1s, w2s, w3s);
  argmin_k<<<dim3(64, 64), 256, 0, stream>>>(pf_hi, pf_lo, cb_hi, cb_lo, cnorm, keys);
  gather_k<<<1024, 256, 0, stream>>>(keys, cb_hi, quant);
  gemm_bf_k<8, 8, 8, true><<<dim3(4, 64), 256, 0, stream>>>(quant, w1s, b1, 16, h1);
  gemm_bf_k<8, 4, 16, true><<<dim3(4, 64), 256, 0, stream>>>(h1, w2s, b2, 8, h2);
  gemm3_chamfer_k<<<128, 256, 0, stream>>>(h2, w3s, b3, neigh, out);
}

// Round 5
// 207.955 us; speedup vs baseline: 4.8583x; 1.3112x over previous
//
#include <hip/hip_runtime.h>
#include <hip/hip_bf16.h>
#include <float.h>

#define NTOK 8192   // B*G tokens
#define NCB  8192   // codebook entries
#define CDIM 256
#define KPTS 32
#define SQNT 24.0f  // i8 quantization scale
#define INV_S2 (1.0f / (SQNT * SQNT))

typedef __attribute__((ext_vector_type(8))) short short8;   // 8 bf16
typedef __attribute__((ext_vector_type(4))) float f32x4;
typedef __attribute__((ext_vector_type(4))) int i32x4;
typedef unsigned int u32;
typedef unsigned long long u64;

__device__ __forceinline__ void gl_lds16(const void* g, void* l) {
  __builtin_amdgcn_global_load_lds(
      (const __attribute__((address_space(1))) u32*)(g),
      (__attribute__((address_space(3))) u32*)(l), 16, 0, 0);
}

__device__ __forceinline__ ushort bf16_rne(float x) {
  u32 u = __float_as_uint(x);
  return (ushort)((u + 0x7fffu + ((u >> 16) & 1u)) >> 16);
}

__device__ __forceinline__ int pack4i8(int a, int b, int c, int d) {
  return (a & 0xff) | ((b & 0xff) << 8) | ((c & 0xff) << 16) | ((d & 0xff) << 24);
}

// ---------------- fused prep: i8 splits, cb bf16 frags, weights, cnorm ----
// i8 frag layout: [tile=row>>4][kb64=k>>6] block of 1KB; lane=quad*16+r16
//   holds row=tile*16+r16, k=kb64*64+quad*16+j at byte j.
// bf16 frag layout: [tile][kb32] block of 1KB; lane=((k>>3)&3)*16+r16, 8 elems.
__global__ __launch_bounds__(256) void prep_k(
    const float* __restrict__ pf, const float* __restrict__ cb,
    const float* __restrict__ w1, const float* __restrict__ w2,
    const float* __restrict__ w3,
    i32x4* __restrict__ pf1, i32x4* __restrict__ pf2,
    i32x4* __restrict__ cb1, i32x4* __restrict__ cb2,
    ushort* __restrict__ cb_bf, ushort* __restrict__ w1s,
    ushort* __restrict__ w2s, ushort* __restrict__ w3s,
    float* __restrict__ cnorm) {
  int gid = blockIdx.x * 4 + (threadIdx.x >> 6);
  int lane = threadIdx.x & 63, r16 = lane & 15, quad = lane >> 4;
  if (gid < 4096) {
    // i8 two-level split: pf tasks [0,2048), cb tasks [2048,4096)
    bool is_cb = gid >= 2048;
    int t = is_cb ? gid - 2048 : gid;
    int tile = t >> 2, kb = t & 3;
    const float* src = is_cb ? cb : pf;
    int row = tile * 16 + r16;
    const float* sp = src + (size_t)row * CDIM + kb * 64 + quad * 16;
    float4 v0 = ((const float4*)sp)[0];
    float4 v1 = ((const float4*)sp)[1];
    float4 v2 = ((const float4*)sp)[2];
    float4 v3 = ((const float4*)sp)[3];
    float x[16] = {v0.x, v0.y, v0.z, v0.w, v1.x, v1.y, v1.z, v1.w,
                   v2.x, v2.y, v2.z, v2.w, v3.x, v3.y, v3.z, v3.w};
    int q1[16], q2[16];
    float s = 0.f;
#pragma unroll
    for (int e = 0; e < 16; e++) {
      float as = x[e] * SQNT;
      float a1 = rintf(as);
      a1 = fminf(fmaxf(a1, -127.f), 127.f);
      float a2 = rintf((as - a1) * 128.f);
      a2 = fminf(fmaxf(a2, -127.f), 127.f);
      q1[e] = (int)a1;
      q2[e] = (int)a2;
      s += x[e] * x[e];
    }
    i32x4 p1 = {pack4i8(q1[0], q1[1], q1[2], q1[3]),
                pack4i8(q1[4], q1[5], q1[6], q1[7]),
                pack4i8(q1[8], q1[9], q1[10], q1[11]),
                pack4i8(q1[12], q1[13], q1[14], q1[15])};
    i32x4 p2 = {pack4i8(q2[0], q2[1], q2[2], q2[3]),
                pack4i8(q2[4], q2[5], q2[6], q2[7]),
                pack4i8(q2[8], q2[9], q2[10], q2[11]),
                pack4i8(q2[12], q2[13], q2[14], q2[15])};
    size_t o = (size_t)t * 64 + lane;
    (is_cb ? cb1 : pf1)[o] = p1;
    (is_cb ? cb2 : pf2)[o] = p2;
    if (is_cb) {
      s += __shfl_xor(s, 16, 64);
      s += __shfl_xor(s, 32, 64);
      if (quad == 0) atomicAdd(cnorm + row, s);
    }
  } else if (gid < 8192) {
    // cb -> bf16 fragment order (for gather + MLP)
    int t = gid - 4096;
    int tile = t >> 3, kb = t & 7;
    int row = tile * 16 + r16;
    const float* sp = cb + (size_t)row * CDIM + kb * 32 + quad * 8;
    float4 a = ((const float4*)sp)[0];
    float4 b = ((const float4*)sp)[1];
    short8 vh = {(short)bf16_rne(a.x), (short)bf16_rne(a.y),
                 (short)bf16_rne(a.z), (short)bf16_rne(a.w),
                 (short)bf16_rne(b.x), (short)bf16_rne(b.y),
                 (short)bf16_rne(b.z), (short)bf16_rne(b.w)};
    *(short8*)(cb_bf + ((size_t)tile * 8 + kb) * 512 + lane * 8) = vh;
  } else if (gid < 8752) {
    // weights -> bf16 fragment order
    int t = gid - 8192;
    const float* src;
    ushort* dst;
    int KB;
    if (t < 256)      { src = w1; dst = w1s; KB = 8; }
    else if (t < 512) { src = w2; dst = w2s; KB = 16; t -= 256; }
    else              { src = w3; dst = w3s; KB = 8;  t -= 512; }
    int tile = t / KB, kb = t - tile * KB, K = KB * 32;
    int row = tile * 16 + r16;
    const float* sp = src + (size_t)row * K + kb * 32 + quad * 8;
    float4 a = ((const float4*)sp)[0];
    float4 b = ((const float4*)sp)[1];
    short8 vh = {(short)bf16_rne(a.x), (short)bf16_rne(a.y),
                 (short)bf16_rne(a.z), (short)bf16_rne(a.w),
                 (short)bf16_rne(b.x), (short)bf16_rne(b.y),
                 (short)bf16_rne(b.z), (short)bf16_rne(b.w)};
    *(short8*)(dst + ((size_t)tile * KB + kb) * 512 + lane * 8) = vh;
  }
}

// -------- i8 MFMA distance GEMM + argmin, atomic-free --------
// d = |c|^2 - 2 p.c ; p.c*S^2 = M11 + (M12+M21)/128  (A2B2/128^2 dropped)
// grid (8 nsplit, 64 mt); block loops 8 col-subtiles of 128, keeps running
// best in registers, stores one candidate per (row, wave-col-half).
__global__ __launch_bounds__(256, 2) void argmin_k(
    const char* __restrict__ A1g, const char* __restrict__ A2g,
    const char* __restrict__ B1g, const char* __restrict__ B2g,
    const float* __restrict__ cnorm, u64* __restrict__ pkeys) {
  __shared__ char lds[32 * 1024];
  int tid = threadIdx.x;
  int ns = blockIdx.x, mt = blockIdx.y;
  int wv = tid >> 6, lane = tid & 63;
  int quad = lane >> 4, r16 = lane & 15;
  int wr = wv >> 1, wc = wv & 1;

  float bv[4][4];
  int bi[4][4];
#pragma unroll
  for (int i = 0; i < 4; i++)
#pragma unroll
    for (int r = 0; r < 4; r++) { bv[i][r] = FLT_MAX; bi[i][r] = 0x7fffffff; }

  const char* bsrc = (wv == 0) ? A1g : (wv == 1) ? A2g : (wv == 2) ? B1g : B2g;

  for (int nts = 0; nts < 8; ++nts) {
    int nt = ns * 8 + nts;
    i32x4 am[4][4], ac[4][4];
#pragma unroll
    for (int i = 0; i < 4; i++)
#pragma unroll
      for (int j = 0; j < 4; j++) {
        am[i][j] = (i32x4){0, 0, 0, 0};
        ac[i][j] = (i32x4){0, 0, 0, 0};
      }
    for (int kb = 0; kb < 4; ++kb) {
#pragma unroll
      for (int u = 0; u < 8; ++u) {
        int gt = ((wv < 2) ? mt : nt) * 8 + u;
        gl_lds16(bsrc + ((size_t)gt * 4 + kb) * 1024 + lane * 16,
                 lds + (wv * 8 + u) * 1024);
      }
      __syncthreads();
      i32x4 f1[4], f2[4], g1[4], g2[4];
#pragma unroll
      for (int i = 0; i < 4; i++) {
        f1[i] = *(const i32x4*)(lds + (wr * 4 + i) * 1024 + lane * 16);
        f2[i] = *(const i32x4*)(lds + (8 + wr * 4 + i) * 1024 + lane * 16);
      }
#pragma unroll
      for (int j = 0; j < 4; j++) {
        g1[j] = *(const i32x4*)(lds + (16 + wc * 4 + j) * 1024 + lane * 16);
        g2[j] = *(const i32x4*)(lds + (24 + wc * 4 + j) * 1024 + lane * 16);
      }
#pragma unroll
      for (int i = 0; i < 4; i++)
#pragma unroll
        for (int j = 0; j < 4; j++) {
          am[i][j] = __builtin_amdgcn_mfma_i32_16x16x64_i8(f1[i], g1[j], am[i][j], 0, 0, 0);
          ac[i][j] = __builtin_amdgcn_mfma_i32_16x16x64_i8(f1[i], g2[j], ac[i][j], 0, 0, 0);
          ac[i][j] = __builtin_amdgcn_mfma_i32_16x16x64_i8(f2[i], g1[j], ac[i][j], 0, 0, 0);
        }
      __syncthreads();
    }
    // fold this 128-col subtile into running best
#pragma unroll
    for (int j = 0; j < 4; j++) {
      int col = nt * 128 + wc * 64 + j * 16 + r16;
      float cn = cnorm[col];
#pragma unroll
      for (int i = 0; i < 4; i++)
#pragma unroll
        for (int r = 0; r < 4; r++) {
          float d = cn - 2.f * INV_S2 *
                            ((float)am[i][j][r] + (float)ac[i][j][r] * 0.0078125f);
          if (d < bv[i][r] || (d == bv[i][r] && col < bi[i][r])) {
            bv[i][r] = d;
            bi[i][r] = col;
          }
        }
    }
  }
  // reduce across the 16 col-lanes (r16), first-index tie-break
#pragma unroll
  for (int m = 1; m < 16; m <<= 1) {
#pragma unroll
    for (int i = 0; i < 4; i++)
#pragma unroll
      for (int r = 0; r < 4; r++) {
        float ov = __shfl_xor(bv[i][r], m, 64);
        int oi = __shfl_xor(bi[i][r], m, 64);
        if (ov < bv[i][r] || (ov == bv[i][r] && oi < bi[i][r])) {
          bv[i][r] = ov;
          bi[i][r] = oi;
        }
      }
  }
  if (r16 == 0) {
#pragma unroll
    for (int i = 0; i < 4; i++)
#pragma unroll
      for (int r = 0; r < 4; r++) {
        int row = mt * 128 + wr * 64 + i * 16 + quad * 4 + r;
        u32 u = __float_as_uint(bv[i][r]);
        u32 mk = (u & 0x80000000u) ? ~u : (u | 0x80000000u);
        pkeys[(size_t)(ns * 2 + wc) * NTOK + row] = ((u64)mk << 32) | (u32)bi[i][r];
      }
  }
}

// ---- merge 16 candidate slots + gather bf16 codebook fragments ----
__global__ __launch_bounds__(256) void gather_k(const u64* __restrict__ pkeys,
                                                const ushort* __restrict__ cb_bf,
                                                ushort* __restrict__ quant) {
  int gid = blockIdx.x * 4 + (threadIdx.x >> 6);
  int lane = threadIdx.x & 63, r16 = lane & 15, quad = lane >> 4;
  int tile = gid >> 3, kb = gid & 7;
  int row = tile * 16 + r16;
  u64 best = pkeys[row];
#pragma unroll
  for (int s = 1; s < 16; s++) {
    u64 v = pkeys[(size_t)s * NTOK + row];
    if (v < best) best = v;
  }
  int id = (int)(u32)best;
  short8 v = *(const short8*)(cb_bf + ((size_t)(id >> 4) * 8 + kb) * 512 +
                              (size_t)((id & 15) + quad * 16) * 8);
  *(short8*)(quant + ((size_t)tile * 8 + kb) * 512 + lane * 8) = v;
}

// -------- single-bf16 MFMA GEMM: C = A * B^T + bias [, relu] --------
template <int BM, int BN, int KB, bool RELU>
__global__ __launch_bounds__(256, 2) void gemm_bf_k(
    const ushort* __restrict__ Ag, const ushort* __restrict__ Bg,
    const float* __restrict__ bias, int okb, ushort* __restrict__ obf) {
  constexpr int NC = BM + BN;
  constexpr int WM = BM / 2, WN = BN / 2;
  __shared__ ushort lds[NC * 512];
  int tid = threadIdx.x;
  int ntB = blockIdx.x, mtB = blockIdx.y;
  int wv = tid >> 6, lane = tid & 63;
  int quad = lane >> 4, r16 = lane & 15;
  int wr = wv >> 1, wc = wv & 1;

  f32x4 acc[WM][WN];
#pragma unroll
  for (int i = 0; i < WM; i++)
#pragma unroll
    for (int j = 0; j < WN; j++) acc[i][j] = (f32x4){0.f, 0.f, 0.f, 0.f};

  for (int kb = 0; kb < KB; ++kb) {
    for (int c = wv; c < NC; c += 4) {
      const ushort* base;
      int gt;
      if (c < BM) { base = Ag; gt = mtB * BM + c; }
      else        { base = Bg; gt = ntB * BN + (c - BM); }
      gl_lds16(base + ((size_t)gt * KB + kb) * 512 + lane * 8, lds + c * 512);
    }
    __syncthreads();
    short8 fa[WM], fb[WN];
#pragma unroll
    for (int i = 0; i < WM; i++)
      fa[i] = *(const short8*)(lds + (wr * WM + i) * 512 + lane * 8);
#pragma unroll
    for (int j = 0; j < WN; j++)
      fb[j] = *(const short8*)(lds + (BM + wc * WN + j) * 512 + lane * 8);
#pragma unroll
    for (int i = 0; i < WM; i++)
#pragma unroll
      for (int j = 0; j < WN; j++)
        acc[i][j] = __builtin_amdgcn_mfma_f32_16x16x32_bf16(fa[i], fb[j], acc[i][j], 0, 0, 0);
    __syncthreads();
  }

#pragma unroll
  for (int j = 0; j < WN; j++) {
    int col = ntB * BN * 16 + (wc * WN + j) * 16 + r16;
    float bj = bias[col];
#pragma unroll
    for (int i = 0; i < WM; i++) {
#pragma unroll
      for (int reg = 0; reg < 4; reg++) {
        int row = mtB * BM * 16 + (wr * WM + i) * 16 + quad * 4 + reg;
        float v = acc[i][j][reg] + bj;
        if (RELU) v = fmaxf(v, 0.f);
        size_t o = ((size_t)(row >> 4) * okb + (col >> 5)) * 512 +
                   (size_t)(((col >> 3) & 3) * 16 + (row & 15)) * 8 + (col & 7);
        obf[o] = bf16_rne(v);
      }
    }
  }
}

// -------- layer-3 GEMM (64 tokens x 96 outs per block) fused with chamfer ----
__global__ __launch_bounds__(256) void gemm3_chamfer_k(
    const ushort* __restrict__ Ag, const ushort* __restrict__ Bg,
    const float* __restrict__ bias, const float* __restrict__ neigh,
    float* __restrict__ out) {
  constexpr int BM = 4, BN = 6, KB = 8, WM = 2, WN = 3, NC = 10;
  __shared__ ushort lds[NC * 512];
  __shared__ float rec[64][96];
  __shared__ float gts[64][96];
  __shared__ float wsum[4];
  int tid = threadIdx.x;
  int mtB = blockIdx.x;
  int wv = tid >> 6, lane = tid & 63;
  int quad = lane >> 4, r16 = lane & 15;
  int wr = wv >> 1, wc = wv & 1;

  f32x4 acc[WM][WN];
#pragma unroll
  for (int i = 0; i < WM; i++)
#pragma unroll
    for (int j = 0; j < WN; j++) acc[i][j] = (f32x4){0.f, 0.f, 0.f, 0.f};

  for (int kb = 0; kb < KB; ++kb) {
    for (int c = wv; c < NC; c += 4) {
      const ushort* base;
      int gt;
      if (c < BM) { base = Ag; gt = mtB * BM + c; }
      else        { base = Bg; gt = c - BM; }
      gl_lds16(base + ((size_t)gt * KB + kb) * 512 + lane * 8, lds + c * 512);
    }
    __syncthreads();
    short8 fa[WM], fb[WN];
#pragma unroll
    for (int i = 0; i < WM; i++)
      fa[i] = *(const short8*)(lds + (wr * WM + i) * 512 + lane * 8);
#pragma unroll
    for (int j = 0; j < WN; j++)
      fb[j] = *(const short8*)(lds + (BM + wc * WN + j) * 512 + lane * 8);
#pragma unroll
    for (int i = 0; i < WM; i++)
#pragma unroll
      for (int j = 0; j < WN; j++)
        acc[i][j] = __builtin_amdgcn_mfma_f32_16x16x32_bf16(fa[i], fb[j], acc[i][j], 0, 0, 0);
    __syncthreads();
  }

#pragma unroll
  for (int j = 0; j < WN; j++) {
    int col = (wc * WN + j) * 16 + r16;
    float bj = bias[col];
#pragma unroll
    for (int i = 0; i < WM; i++) {
#pragma unroll
      for (int reg = 0; reg < 4; reg++) {
        int rl = (wr * WM + i) * 16 + quad * 4 + reg;
        rec[rl][col] = acc[i][j][reg] + bj;
      }
    }
  }
#pragma unroll
  for (int s = 0; s < 6; s++) {
    int idx = tid + s * 256;
    int t = idx / 24, c = (idx - t * 24) * 4;
    *(float4*)&gts[t][c] = *(const float4*)(neigh + (size_t)(mtB * 64 + t) * 96 + c);
  }
  __syncthreads();

  float local = 0.f;
#pragma unroll
  for (int pp = 0; pp < 8; ++pp) {
    int p = tid + pp * 256;
    int t = p >> 5, i = p & 31;
    float rx = rec[t][3 * i], ry = rec[t][3 * i + 1], rz = rec[t][3 * i + 2];
    float gx = gts[t][3 * i], gy = gts[t][3 * i + 1], gz = gts[t][3 * i + 2];
    float mA = FLT_MAX, mB = FLT_MAX;
#pragma unroll
    for (int j = 0; j < 32; j++) {
      float dx = rx - gts[t][3 * j], dy = ry - gts[t][3 * j + 1], dz = rz - gts[t][3 * j + 2];
      float d = dx * dx + dy * dy + dz * dz;
      mA = fminf(mA, d);
      dx = rec[t][3 * j] - gx; dy = rec[t][3 * j + 1] - gy; dz = rec[t][3 * j + 2] - gz;
      d = dx * dx + dy * dy + dz * dz;
      mB = fminf(mB, d);
    }
    local += mA + mB;
  }
#pragma unroll
  for (int off = 32; off; off >>= 1) local += __shfl_down(local, off, 64);
  if ((tid & 63) == 0) wsum[tid >> 6] = local;
  __syncthreads();
  if (tid == 0) {
    float s = wsum[0] + wsum[1] + wsum[2] + wsum[3];
    atomicAdd(out, s * (1.0f / (float)(NTOK * KPTS)));
  }
}

extern "C" void kernel_launch(void* const* d_in, const int* in_sizes, int n_in,
                              void* d_out, int out_size, void* d_ws, size_t ws_size,
                              hipStream_t stream) {
  const float* pf    = (const float*)d_in[0];
  const float* neigh = (const float*)d_in[1];
  const float* cb    = (const float*)d_in[2];
  const float* w1    = (const float*)d_in[3];
  const float* b1    = (const float*)d_in[4];
  const float* w2    = (const float*)d_in[5];
  const float* b2    = (const float*)d_in[6];
  const float* w3    = (const float*)d_in[7];
  const float* b3    = (const float*)d_in[8];
  float* out = (float*)d_out;
  char* base = (char*)d_ws;

  u64*   pkeys = (u64*)base;                       // 16*8192*8 = 1 MB
  float* cnorm = (float*)(base + 0x100000);        // 32 KB
  char*  pf1   = base + 0x110000;                  // 2 MB each
  char*  pf2   = base + 0x310000;
  char*  cb1   = base + 0x510000;
  char*  cb2   = base + 0x710000;
  ushort* cb_bf = (ushort*)(base + 0x910000);      // 4 MB
  ushort* quant = (ushort*)(base + 0xD10000);      // 4 MB
  ushort* h1    = (ushort*)(base + 0x1110000);     // 8 MB
  ushort* h2    = (ushort*)(base + 0x1910000);     // 4 MB
  ushort* w1s   = (ushort*)(base + 0x1D10000);     // 256 KB
  ushort* w2s   = (ushort*)(base + 0x1D50000);     // 256 KB
  ushort* w3s   = (ushort*)(base + 0x1D90000);     // 48 KB

  hipMemsetAsync(d_out, 0, sizeof(float), stream);
  hipMemsetAsync(cnorm, 0, NCB * sizeof(float), stream);
  prep_k<<<2188, 256, 0, stream>>>(pf, cb, w1, w2, w3,
                                   (i32x4*)pf1, (i32x4*)pf2, (i32x4*)cb1,
                                   (i32x4*)cb2, cb_bf, w1s, w2s, w3s, cnorm);
  argmin_k<<<dim3(8, 64), 256, 0, stream>>>(pf1, pf2, cb1, cb2, cnorm, pkeys);
  gather_k<<<1024, 256, 0, stream>>>(pkeys, cb_bf, quant);
  gemm_bf_k<8, 8, 8, true><<<dim3(4, 64), 256, 0, stream>>>(quant, w1s, b1, 16, h1);
  gemm_bf_k<8, 4, 16, true><<<dim3(4, 64), 256, 0, stream>>>(h1, w2s, b2, 8, h2);
  gemm3_chamfer_k<<<128, 256, 0, stream>>>(h2, w3s, b3, neigh, out);
}

// Round 6
// 170.040 us; speedup vs baseline: 5.9416x; 1.2230x over previous
//
#include <hip/hip_runtime.h>
#include <hip/hip_bf16.h>
#include <float.h>

#define NTOK 8192   // B*G tokens
#define NCB  8192   // codebook entries
#define CDIM 256
#define KPTS 32
#define SQNT 24.0f  // i8 quantization scale
#define INV_CFOLD (SQNT * SQNT * 64.0f)   // d / CFOLD scale, CFOLD = 2/(S^2*128)

typedef __attribute__((ext_vector_type(8))) short short8;   // 8 bf16
typedef __attribute__((ext_vector_type(4))) float f32x4;
typedef __attribute__((ext_vector_type(4))) int i32x4;
typedef unsigned int u32;
typedef unsigned long long u64;

__device__ __forceinline__ void gl_lds16(const void* g, void* l) {
  __builtin_amdgcn_global_load_lds(
      (const __attribute__((address_space(1))) u32*)(g),
      (__attribute__((address_space(3))) u32*)(l), 16, 0, 0);
}

__device__ __forceinline__ ushort bf16_rne(float x) {
  u32 u = __float_as_uint(x);
  return (ushort)((u + 0x7fffu + ((u >> 16) & 1u)) >> 16);
}

__device__ __forceinline__ int pack4i8(int a, int b, int c, int d) {
  return (a & 0xff) | ((b & 0xff) << 8) | ((c & 0xff) << 16) | ((d & 0xff) << 24);
}

// ---------------- fused prep: i8 splits, cb bf16 frags, weights, cnorm ----
__global__ __launch_bounds__(256) void prep_k(
    const float* __restrict__ pf, const float* __restrict__ cb,
    const float* __restrict__ w1, const float* __restrict__ w2,
    const float* __restrict__ w3,
    i32x4* __restrict__ pf1, i32x4* __restrict__ pf2,
    i32x4* __restrict__ cb1, i32x4* __restrict__ cb2,
    ushort* __restrict__ cb_bf, ushort* __restrict__ w1s,
    ushort* __restrict__ w2s, ushort* __restrict__ w3s,
    float* __restrict__ cnorm) {
  int gid = blockIdx.x * 4 + (threadIdx.x >> 6);
  int lane = threadIdx.x & 63, r16 = lane & 15, quad = lane >> 4;
  if (gid < 4096) {
    bool is_cb = gid >= 2048;
    int t = is_cb ? gid - 2048 : gid;
    int tile = t >> 2, kb = t & 3;
    const float* src = is_cb ? cb : pf;
    int row = tile * 16 + r16;
    const float* sp = src + (size_t)row * CDIM + kb * 64 + quad * 16;
    float4 v0 = ((const float4*)sp)[0];
    float4 v1 = ((const float4*)sp)[1];
    float4 v2 = ((const float4*)sp)[2];
    float4 v3 = ((const float4*)sp)[3];
    float x[16] = {v0.x, v0.y, v0.z, v0.w, v1.x, v1.y, v1.z, v1.w,
                   v2.x, v2.y, v2.z, v2.w, v3.x, v3.y, v3.z, v3.w};
    int q1[16], q2[16];
    float s = 0.f;
#pragma unroll
    for (int e = 0; e < 16; e++) {
      float as = x[e] * SQNT;
      float a1 = rintf(as);
      a1 = fminf(fmaxf(a1, -127.f), 127.f);
      float a2 = rintf((as - a1) * 128.f);
      a2 = fminf(fmaxf(a2, -127.f), 127.f);
      q1[e] = (int)a1;
      q2[e] = (int)a2;
      s += x[e] * x[e];
    }
    i32x4 p1 = {pack4i8(q1[0], q1[1], q1[2], q1[3]),
                pack4i8(q1[4], q1[5], q1[6], q1[7]),
                pack4i8(q1[8], q1[9], q1[10], q1[11]),
                pack4i8(q1[12], q1[13], q1[14], q1[15])};
    i32x4 p2 = {pack4i8(q2[0], q2[1], q2[2], q2[3]),
                pack4i8(q2[4], q2[5], q2[6], q2[7]),
                pack4i8(q2[8], q2[9], q2[10], q2[11]),
                pack4i8(q2[12], q2[13], q2[14], q2[15])};
    size_t o = (size_t)t * 64 + lane;
    (is_cb ? cb1 : pf1)[o] = p1;
    (is_cb ? cb2 : pf2)[o] = p2;
    if (is_cb) {
      s += __shfl_xor(s, 16, 64);
      s += __shfl_xor(s, 32, 64);
      if (quad == 0) atomicAdd(cnorm + row, s);
    }
  } else if (gid < 8192) {
    int t = gid - 4096;
    int tile = t >> 3, kb = t & 7;
    int row = tile * 16 + r16;
    const float* sp = cb + (size_t)row * CDIM + kb * 32 + quad * 8;
    float4 a = ((const float4*)sp)[0];
    float4 b = ((const float4*)sp)[1];
    short8 vh = {(short)bf16_rne(a.x), (short)bf16_rne(a.y),
                 (short)bf16_rne(a.z), (short)bf16_rne(a.w),
                 (short)bf16_rne(b.x), (short)bf16_rne(b.y),
                 (short)bf16_rne(b.z), (short)bf16_rne(b.w)};
    *(short8*)(cb_bf + ((size_t)tile * 8 + kb) * 512 + lane * 8) = vh;
  } else if (gid < 8752) {
    int t = gid - 8192;
    const float* src;
    ushort* dst;
    int KB;
    if (t < 256)      { src = w1; dst = w1s; KB = 8; }
    else if (t < 512) { src = w2; dst = w2s; KB = 16; t -= 256; }
    else              { src = w3; dst = w3s; KB = 8;  t -= 512; }
    int tile = t / KB, kb = t - tile * KB, K = KB * 32;
    int row = tile * 16 + r16;
    const float* sp = src + (size_t)row * K + kb * 32 + quad * 8;
    float4 a = ((const float4*)sp)[0];
    float4 b = ((const float4*)sp)[1];
    short8 vh = {(short)bf16_rne(a.x), (short)bf16_rne(a.y),
                 (short)bf16_rne(a.z), (short)bf16_rne(a.w),
                 (short)bf16_rne(b.x), (short)bf16_rne(b.y),
                 (short)bf16_rne(b.z), (short)bf16_rne(b.w)};
    *(short8*)(dst + ((size_t)tile * KB + kb) * 512 + lane * 8) = vh;
  }
}

// -------- i8 MFMA distance GEMM + argmin, atomic-free, integer fold --------
// grid (16 nsplit, 64 mt); 4 col-subtiles of 128 per block; 32 slots/row.
__global__ __launch_bounds__(256, 2) void argmin_k(
    const char* __restrict__ A1g, const char* __restrict__ A2g,
    const char* __restrict__ B1g, const char* __restrict__ B2g,
    const float* __restrict__ cnorm, u64* __restrict__ pkeys) {
  __shared__ char lds[32 * 1024];
  int tid = threadIdx.x;
  int ns = blockIdx.x, mt = blockIdx.y;
  int wv = tid >> 6, lane = tid & 63;
  int quad = lane >> 4, r16 = lane & 15;
  int wr = wv >> 1, wc = wv & 1;

  int bvi[4][4], bii[4][4];
#pragma unroll
  for (int i = 0; i < 4; i++)
#pragma unroll
    for (int r = 0; r < 4; r++) { bvi[i][r] = 0x7fffffff; bii[i][r] = 0x7fffffff; }

  const char* bsrc = (wv == 0) ? A1g : (wv == 1) ? A2g : (wv == 2) ? B1g : B2g;

  for (int nts = 0; nts < 4; ++nts) {
    int nt = ns * 4 + nts;
    i32x4 am[4][4], ac[4][4];
#pragma unroll
    for (int i = 0; i < 4; i++)
#pragma unroll
      for (int j = 0; j < 4; j++) {
        am[i][j] = (i32x4){0, 0, 0, 0};
        ac[i][j] = (i32x4){0, 0, 0, 0};
      }
    for (int kb = 0; kb < 4; ++kb) {
#pragma unroll
      for (int u = 0; u < 8; ++u) {
        int gt = ((wv < 2) ? mt : nt) * 8 + u;
        gl_lds16(bsrc + ((size_t)gt * 4 + kb) * 1024 + lane * 16,
                 lds + (wv * 8 + u) * 1024);
      }
      __syncthreads();
      i32x4 f1[4], f2[4], g1[4], g2[4];
#pragma unroll
      for (int i = 0; i < 4; i++) {
        f1[i] = *(const i32x4*)(lds + (wr * 4 + i) * 1024 + lane * 16);
        f2[i] = *(const i32x4*)(lds + (8 + wr * 4 + i) * 1024 + lane * 16);
      }
#pragma unroll
      for (int j = 0; j < 4; j++) {
        g1[j] = *(const i32x4*)(lds + (16 + wc * 4 + j) * 1024 + lane * 16);
        g2[j] = *(const i32x4*)(lds + (24 + wc * 4 + j) * 1024 + lane * 16);
      }
#pragma unroll
      for (int i = 0; i < 4; i++)
#pragma unroll
        for (int j = 0; j < 4; j++) {
          am[i][j] = __builtin_amdgcn_mfma_i32_16x16x64_i8(f1[i], g1[j], am[i][j], 0, 0, 0);
          ac[i][j] = __builtin_amdgcn_mfma_i32_16x16x64_i8(f1[i], g2[j], ac[i][j], 0, 0, 0);
          ac[i][j] = __builtin_amdgcn_mfma_i32_16x16x64_i8(f2[i], g1[j], ac[i][j], 0, 0, 0);
        }
      __syncthreads();
    }
    // integer fold: di = cni - (am*128 + ac); strict < keeps first index
#pragma unroll
    for (int j = 0; j < 4; j++) {
      int col = nt * 128 + wc * 64 + j * 16 + r16;
      int cni = __float2int_rn(cnorm[col] * INV_CFOLD);
#pragma unroll
      for (int i = 0; i < 4; i++)
#pragma unroll
        for (int r = 0; r < 4; r++) {
          int di = cni - (am[i][j][r] * 128 + ac[i][j][r]);
          if (di < bvi[i][r]) { bvi[i][r] = di; bii[i][r] = col; }
        }
    }
  }
  // reduce across the 16 col-lanes, first-index tie-break
#pragma unroll
  for (int m = 1; m < 16; m <<= 1) {
#pragma unroll
    for (int i = 0; i < 4; i++)
#pragma unroll
      for (int r = 0; r < 4; r++) {
        int ov = __shfl_xor(bvi[i][r], m, 64);
        int oi = __shfl_xor(bii[i][r], m, 64);
        if (ov < bvi[i][r] || (ov == bvi[i][r] && oi < bii[i][r])) {
          bvi[i][r] = ov;
          bii[i][r] = oi;
        }
      }
  }
  if (r16 == 0) {
#pragma unroll
    for (int i = 0; i < 4; i++)
#pragma unroll
      for (int r = 0; r < 4; r++) {
        int row = mt * 128 + wr * 64 + i * 16 + quad * 4 + r;
        u32 mk = (u32)(bvi[i][r] + (1 << 30));
        pkeys[(size_t)(ns * 2 + wc) * NTOK + row] = ((u64)mk << 32) | (u32)bii[i][r];
      }
  }
}

// -------- fused: key-merge + gather + 3-layer MLP + chamfer --------
// 32 tokens per block, 256 blocks. A-frags in LDS, B-frags (weights) from L2.
__global__ __launch_bounds__(256) void mlp_fused_k(
    const u64* __restrict__ pkeys, const ushort* __restrict__ cb_bf,
    const ushort* __restrict__ w1s, const float* __restrict__ b1,
    const ushort* __restrict__ w2s, const float* __restrict__ b2,
    const ushort* __restrict__ w3s, const float* __restrict__ b3,
    const float* __restrict__ neigh, float* __restrict__ out) {
  __shared__ char lds[65536];
  __shared__ int ids[32];
  __shared__ float wsum[4];
  // regions: qs [0,16K) ; h1 [16K,48K) ; h2 [48K,64K)
  // aliases: rec f32[32][96] at 0 (qs dead) ; gts f32[32][96] at 16K (h1 dead)
  ushort* qsp = (ushort*)lds;
  ushort* h1p = (ushort*)(lds + 16384);
  ushort* h2p = (ushort*)(lds + 49152);
  float* recp = (float*)lds;
  float* gtsp = (float*)(lds + 16384);

  int tid = threadIdx.x;
  int t0 = blockIdx.x * 32;
  int wv = tid >> 6, lane = tid & 63;
  int quad = lane >> 4, r16 = lane & 15;
  int mtile = wv >> 1, nh = wv & 1;

  // ---- merge 32 key slots per row ----
  {
    int row_l = tid >> 3, sl = tid & 7;
    u64 best = ~0ull;
#pragma unroll
    for (int s = 0; s < 4; s++) {
      u64 v = pkeys[(size_t)(sl + s * 8) * NTOK + t0 + row_l];
      if (v < best) best = v;
    }
#pragma unroll
    for (int m = 1; m < 8; m <<= 1) {
      u64 o = __shfl_xor((unsigned long long)best, m, 64);
      if (o < best) best = o;
    }
    if (sl == 0) ids[row_l] = (int)(u32)best;
  }
  __syncthreads();

  // ---- gather quant A-frags from cb_bf ----
  {
    int tile_l = wv >> 1, kb0 = (wv & 1) * 4;
    int id = ids[tile_l * 16 + r16];
#pragma unroll
    for (int q = 0; q < 4; q++) {
      int kb = kb0 + q;
      short8 v = *(const short8*)(cb_bf + ((size_t)(id >> 4) * 8 + kb) * 512 +
                                  (size_t)((id & 15) + quad * 16) * 8);
      *(short8*)(qsp + (size_t)(tile_l * 8 + kb) * 512 + lane * 8) = v;
    }
  }
  __syncthreads();

  // ---- layer 1: 256 -> 512, relu ----
  {
    short8 fa[8];
#pragma unroll
    for (int kb = 0; kb < 8; kb++)
      fa[kb] = *(const short8*)(qsp + (size_t)(mtile * 8 + kb) * 512 + lane * 8);
    for (int jt = nh * 16; jt < nh * 16 + 16; ++jt) {
      f32x4 acc = (f32x4){0.f, 0.f, 0.f, 0.f};
#pragma unroll
      for (int kb = 0; kb < 8; kb++) {
        short8 fb = *(const short8*)(w1s + ((size_t)jt * 8 + kb) * 512 + lane * 8);
        acc = __builtin_amdgcn_mfma_f32_16x16x32_bf16(fa[kb], fb, acc, 0, 0, 0);
      }
      int col = jt * 16 + r16;
      float bj = b1[col];
#pragma unroll
      for (int reg = 0; reg < 4; reg++) {
        int row_l = mtile * 16 + quad * 4 + reg;
        float v = fmaxf(acc[reg] + bj, 0.f);
        size_t o = (size_t)((row_l >> 4) * 16 + (col >> 5)) * 512 +
                   (size_t)(((col >> 3) & 3) * 16 + (row_l & 15)) * 8 + (col & 7);
        h1p[o] = bf16_rne(v);
      }
    }
  }
  __syncthreads();

  // ---- layer 2: 512 -> 256, relu ----
  {
    short8 fa[16];
#pragma unroll
    for (int kb = 0; kb < 16; kb++)
      fa[kb] = *(const short8*)(h1p + (size_t)(mtile * 16 + kb) * 512 + lane * 8);
    for (int jt = nh * 8; jt < nh * 8 + 8; ++jt) {
      f32x4 acc = (f32x4){0.f, 0.f, 0.f, 0.f};
#pragma unroll
      for (int kb = 0; kb < 16; kb++) {
        short8 fb = *(const short8*)(w2s + ((size_t)jt * 16 + kb) * 512 + lane * 8);
        acc = __builtin_amdgcn_mfma_f32_16x16x32_bf16(fa[kb], fb, acc, 0, 0, 0);
      }
      int col = jt * 16 + r16;
      float bj = b2[col];
#pragma unroll
      for (int reg = 0; reg < 4; reg++) {
        int row_l = mtile * 16 + quad * 4 + reg;
        float v = fmaxf(acc[reg] + bj, 0.f);
        size_t o = (size_t)((row_l >> 4) * 8 + (col >> 5)) * 512 +
                   (size_t)(((col >> 3) & 3) * 16 + (row_l & 15)) * 8 + (col & 7);
        h2p[o] = bf16_rne(v);
      }
    }
  }
  __syncthreads();

  // ---- stage ground truth into h1 region (dead) ----
#pragma unroll
  for (int s = 0; s < 3; s++) {
    int idx = tid + s * 256;
    int t = idx / 24, c = (idx - t * 24) * 4;
    *(float4*)(gtsp + (size_t)t * 96 + c) =
        *(const float4*)(neigh + (size_t)(t0 + t) * 96 + c);
  }

  // ---- layer 3: 256 -> 96 -> rec in LDS (qs region, dead) ----
  {
    short8 fa[8];
#pragma unroll
    for (int kb = 0; kb < 8; kb++)
      fa[kb] = *(const short8*)(h2p + (size_t)(mtile * 8 + kb) * 512 + lane * 8);
#pragma unroll
    for (int jj = 0; jj < 3; ++jj) {
      int jt = nh * 3 + jj;
      f32x4 acc = (f32x4){0.f, 0.f, 0.f, 0.f};
#pragma unroll
      for (int kb = 0; kb < 8; kb++) {
        short8 fb = *(const short8*)(w3s + ((size_t)jt * 8 + kb) * 512 + lane * 8);
        acc = __builtin_amdgcn_mfma_f32_16x16x32_bf16(fa[kb], fb, acc, 0, 0, 0);
      }
      int col = jt * 16 + r16;
      float bj = b3[col];
#pragma unroll
      for (int reg = 0; reg < 4; reg++) {
        int row_l = mtile * 16 + quad * 4 + reg;
        recp[(size_t)row_l * 96 + col] = acc[reg] + bj;
      }
    }
  }
  __syncthreads();

  // ---- chamfer ----
  float local = 0.f;
#pragma unroll
  for (int pp = 0; pp < 4; ++pp) {
    int p = tid + pp * 256;
    int t = p >> 5, i = p & 31;
    float rx = recp[t * 96 + 3 * i], ry = recp[t * 96 + 3 * i + 1], rz = recp[t * 96 + 3 * i + 2];
    float gx = gtsp[t * 96 + 3 * i], gy = gtsp[t * 96 + 3 * i + 1], gz = gtsp[t * 96 + 3 * i + 2];
    float mA = FLT_MAX, mB = FLT_MAX;
#pragma unroll
    for (int j = 0; j < 32; j++) {
      float dx = rx - gtsp[t * 96 + 3 * j], dy = ry - gtsp[t * 96 + 3 * j + 1],
            dz = rz - gtsp[t * 96 + 3 * j + 2];
      float d = dx * dx + dy * dy + dz * dz;
      mA = fminf(mA, d);
      dx = recp[t * 96 + 3 * j] - gx; dy = recp[t * 96 + 3 * j + 1] - gy;
      dz = recp[t * 96 + 3 * j + 2] - gz;
      d = dx * dx + dy * dy + dz * dz;
      mB = fminf(mB, d);
    }
    local += mA + mB;
  }
#pragma unroll
  for (int off = 32; off; off >>= 1) local += __shfl_down(local, off, 64);
  if ((tid & 63) == 0) wsum[tid >> 6] = local;
  __syncthreads();
  if (tid == 0) {
    float s = wsum[0] + wsum[1] + wsum[2] + wsum[3];
    atomicAdd(out, s * (1.0f / (float)(NTOK * KPTS)));
  }
}

extern "C" void kernel_launch(void* const* d_in, const int* in_sizes, int n_in,
                              void* d_out, int out_size, void* d_ws, size_t ws_size,
                              hipStream_t stream) {
  const float* pf    = (const float*)d_in[0];
  const float* neigh = (const float*)d_in[1];
  const float* cb    = (const float*)d_in[2];
  const float* w1    = (const float*)d_in[3];
  const float* b1    = (const float*)d_in[4];
  const float* w2    = (const float*)d_in[5];
  const float* b2    = (const float*)d_in[6];
  const float* w3    = (const float*)d_in[7];
  const float* b3    = (const float*)d_in[8];
  float* out = (float*)d_out;
  char* base = (char*)d_ws;

  u64*   pkeys = (u64*)base;                       // 32*8192*8 = 2 MB
  float* cnorm = (float*)(base + 0x200000);        // 32 KB
  char*  pf1   = base + 0x210000;                  // 2 MB each
  char*  pf2   = base + 0x410000;
  char*  cb1   = base + 0x610000;
  char*  cb2   = base + 0x810000;
  ushort* cb_bf = (ushort*)(base + 0xA10000);      // 4 MB
  ushort* w1s   = (ushort*)(base + 0xE10000);      // 256 KB
  ushort* w2s   = (ushort*)(base + 0xE50000);      // 256 KB
  ushort* w3s   = (ushort*)(base + 0xE90000);      // 48 KB

  hipMemsetAsync(d_out, 0, sizeof(float), stream);
  hipMemsetAsync(cnorm, 0, NCB * sizeof(float), stream);
  prep_k<<<2188, 256, 0, stream>>>(pf, cb, w1, w2, w3,
                                   (i32x4*)pf1, (i32x4*)pf2, (i32x4*)cb1,
                                   (i32x4*)cb2, cb_bf, w1s, w2s, w3s, cnorm);
  argmin_k<<<dim3(16, 64), 256, 0, stream>>>(pf1, pf2, cb1, cb2, cnorm, pkeys);
  mlp_fused_k<<<256, 256, 0, stream>>>(pkeys, cb_bf, w1s, b1, w2s, b2, w3s, b3,
                                       neigh, out);
}